// Round 11
// baseline (77.127 us; speedup 1.0000x reference)
//
#include <hip/hip_runtime.h>
#include <math.h>

#define SIDE 0.6
#define NIMP 16

// ---------- fast f64 exp, |x| <= 350, rel err ~1e-15 (validated r3/r4) ----------
__device__ __forceinline__ double exp_fast(double x) {
    const double INVLN2 = 1.44269504088896338700e+00;
    const double LN2HI  = 6.93147180369123816490e-01;
    const double LN2LO  = 1.90821492927058770002e-10;
    const double kd = __builtin_rint(x * INVLN2);
    const int    k  = (int)kd;
    double r = __builtin_fma(-kd, LN2HI, x);
    r        = __builtin_fma(-kd, LN2LO, r);
    double p =               2.08767569878681e-09;
    p = __builtin_fma(p, r,  2.50521083854417e-08);
    p = __builtin_fma(p, r,  2.75573192239859e-07);
    p = __builtin_fma(p, r,  2.75573192239859e-06);
    p = __builtin_fma(p, r,  2.48015873015873e-05);
    p = __builtin_fma(p, r,  1.98412698412698e-04);
    p = __builtin_fma(p, r,  1.38888888888889e-03);
    p = __builtin_fma(p, r,  8.33333333333333e-03);
    p = __builtin_fma(p, r,  4.16666666666667e-02);
    p = __builtin_fma(p, r,  1.66666666666667e-01);
    p = __builtin_fma(p, r,  5.00000000000000e-01);
    p = __builtin_fma(p, r,  1.0);
    p = __builtin_fma(p, r,  1.0);
    const long long bits = (long long)(1023 + k) << 52;
    return p * __longlong_as_double(bits);
}

// ---------- fast f32 exp, |x| <= 40, rel err ~2e-7 (validated r5/r7/r8/r9) ----------
__device__ __forceinline__ float exp_fast_f(float x) {
    const float kd = rintf(x * 1.44269504f);
    const int   k  = (int)kd;
    float r = __builtin_fmaf(-kd, 0.693359375f, x);
    r       = __builtin_fmaf(kd, 2.12194440e-4f, r);
    float p =                1.98412698e-4f;
    p = __builtin_fmaf(p, r, 1.38888889e-3f);
    p = __builtin_fmaf(p, r, 8.33333333e-3f);
    p = __builtin_fmaf(p, r, 4.16666667e-2f);
    p = __builtin_fmaf(p, r, 1.66666667e-1f);
    p = __builtin_fmaf(p, r, 5.00000000e-1f);
    p = __builtin_fmaf(p, r, 1.0f);
    p = __builtin_fmaf(p, r, 1.0f);
    return p * __int_as_float((127 + k) << 23);
}

#if __has_builtin(__builtin_amdgcn_rcpf)
__device__ __forceinline__ float rcp_nr(float x) {   // ~0.5 ulp: v_rcp + 1 NR
    float r = __builtin_amdgcn_rcpf(x);
    return __builtin_fmaf(__builtin_fmaf(-x, r, 1.0f), r, r);
}
#else
__device__ __forceinline__ float rcp_nr(float x) { return 1.0f / x; }
#endif

// ============================================================================
// Fast kernel: 4 lanes per ray, 16 intervals per lane, SINGLE pass.
// Identical numerics to rounds 9/10. ONLY change vs r10:
// amdgpu_waves_per_eu(4,4) pins the allocator to exactly 4 waves/EU ->
// VGPR budget 128 (r10's launch_bounds(256,4) set only a MIN, which the
// 8-wave heuristic already satisfied at 64 VGPR + spill; VGPR_Count stayed
// 64 and perf was unchanged). ~82 array values + scalars fit in ~110 VGPRs
// with zero scratch.
// ============================================================================
__global__ __attribute__((amdgpu_waves_per_eu(4, 4)))
__launch_bounds__(256) void neus_fast_kernel(
    const float* __restrict__ rays_o,
    const float* __restrict__ rays_d,
    const float* __restrict__ z_vals,
    const float* __restrict__ sdf,
    const float* __restrict__ inv_s,
    float* __restrict__ out,
    unsigned* __restrict__ ctr,
    unsigned* __restrict__ list,
    unsigned cap, int B)
{
    const int tid  = blockIdx.x * 256 + threadIdx.x;
    const int ray  = tid >> 2;          // 4 lanes per ray
    const int sub  = tid & 3;
    if (ray >= B) return;               // all 4 lanes of a live ray are live

    const float* zp = z_vals + (size_t)ray * 64 + sub * 16;
    const float* sp = sdf    + (size_t)ray * 64 + sub * 16;
    const float* ip = inv_s  + (size_t)ray * 63 + sub * 16;

    const float ox = rays_o[(size_t)ray*3+0];
    const float oy = rays_o[(size_t)ray*3+1];
    const float oz = rays_o[(size_t)ray*3+2];
    const float dx = rays_d[(size_t)ray*3+0];
    const float dy = rays_d[(size_t)ray*3+1];
    const float dz = rays_d[(size_t)ray*3+2];

    // ---- loads: lane-contiguous float4 (stride 64B across lanes) ----
    float z[17], s[17];
    #pragma unroll
    for (int q = 0; q < 4; ++q) {
        const float4 a = *reinterpret_cast<const float4*>(zp + q * 4);
        const float4 b = *reinterpret_cast<const float4*>(sp + q * 4);
        z[q*4+0]=a.x; z[q*4+1]=a.y; z[q*4+2]=a.z; z[q*4+3]=a.w;
        s[q*4+0]=b.x; s[q*4+1]=b.y; s[q*4+2]=b.z; s[q*4+3]=b.w;
    }
    z[16] = __shfl_down(z[0], 1);   // next lane's first elem (sub3: unused)
    s[16] = __shfl_down(s[0], 1);

    float iv[16];
    #pragma unroll
    for (int i = 0; i < 15; ++i) iv[i] = ip[i];
    iv[15] = (sub < 3) ? ip[15] : 0.0f;   // global idx 63 would be OOB

    // ---- inside-box bitmask + box flip band ----
    int flag = 0;
    unsigned m = 0;
    #pragma unroll
    for (int i = 0; i < 16; ++i) {
        const float px = __builtin_fmaf(dx, z[i], ox);
        const float py = __builtin_fmaf(dy, z[i], oy);
        const float pz = __builtin_fmaf(dz, z[i], oz);
        const float ax = fabsf(px), ay = fabsf(py), az = fabsf(pz);
        if (ax <= 0.6f && ay <= 0.6f && az <= 0.6f) m |= (1u << i);
        flag |= (fabsf(ax-0.6f) < 1e-5f) | (fabsf(ay-0.6f) < 1e-5f) |
                (fabsf(az-0.6f) < 1e-5f);
    }
    m |= (__shfl_down(m, 1) & 1u) << 16;   // boundary inner bit (sub3: unused)

    // ---- prev_cos carry across lanes ----
    const float cv0_15 = (s[16]-s[15]) * rcp_nr(z[16]-z[15] + 1e-5f);
    float prevc = __shfl_up(cv0_15, 1);
    if (sub == 0) prevc = 0.0f;

    // ---- per-interval alpha, g ----
    float aw[16], g[16];
    float Gloc = 1.0f;
    #pragma unroll
    for (int i = 0; i < 16; ++i) {
        const float cv0 = (s[i+1]-s[i]) * rcp_nr(z[i+1]-z[i] + 1e-5f);
        float cv = fminf(prevc, cv0);
        prevc = cv0;
        const float inside = ((m >> i) & 3u) ? 1.0f : 0.0f;
        cv = fminf(fmaxf(cv, -1000.f), 0.f) * inside;
        const float mid = 0.5f * (s[i] + s[i+1]);
        const float dzz = z[i+1] - z[i];
        const float q2  = cv * (dzz * 0.5f);
        const float apv = (mid - q2) * iv[i];
        const float anv = (mid + q2) * iv[i];
        const float ea = exp_fast_f(fminf(fmaxf(-apv, -40.f), 40.f));
        const float eb = exp_fast_f(fminf(fmaxf(-anv, -40.f), 40.f));
        const float onea = 1.f + ea;
        const float Pp  = onea * (1.f + eb);
        const float Nn  = __builtin_fmaf(1e-5f, Pp, eb - ea);
        const float Dd  = __builtin_fmaf(1e-5f, Pp, 1.f + eb);
        const float invD = rcp_nr(Dd);
        float al = Nn * invD;
        float gg = __builtin_fmaf(onea, invD, 1e-7f);
        if (i == 15 && sub == 3) { al = 0.f; gg = 1.f; }   // j=63 doesn't exist
        aw[i] = al; g[i] = gg;
        Gloc *= gg;
    }

    // ---- cross-lane transmittance base T0 (left-assoc, consistent) ----
    const int lane = threadIdx.x & 63;
    const int gb   = lane & ~3;
    const float G0 = __shfl(Gloc, gb+0);
    const float G1 = __shfl(Gloc, gb+1);
    const float G2 = __shfl(Gloc, gb+2);
    float T0 = 1.0f;
    if (sub > 0) T0 *= G0;
    if (sub > 1) T0 *= G1;
    if (sub > 2) T0 *= G2;

    // ---- weights + local sum ----
    float Tr = T0, Sloc = 0.0f;
    #pragma unroll
    for (int i = 0; i < 16; ++i) {
        float w = __builtin_fmaf(aw[i], Tr, 1e-5f);
        if (i == 15 && sub == 3) w = 0.0f;
        Tr *= g[i];
        Sloc += w;
        aw[i] = w;                       // aw now holds weights
    }

    // ---- canonical boundaries (identical in all 4 lanes: no gaps) ----
    const float S0 = __shfl(Sloc, gb+0);
    const float S1 = __shfl(Sloc, gb+1);
    const float S2 = __shfl(Sloc, gb+2);
    const float S3 = __shfl(Sloc, gb+3);
    const float B1 = S0;
    const float B2 = B1 + S1;
    const float B3 = B2 + S2;
    const float total = B3 + S3;
    const float Bc  = (sub==0) ? 0.f : (sub==1) ? B1 : (sub==2) ? B2 : B3;
    const float Bc1 = (sub==0) ? B1  : (sub==1) ? B2 : (sub==2) ? B3 : total;
    const float bandU = 4e-5f * total;
    const float bandW = 4e-3f * total;

    // ---- k-range owned by this lane (comparison-based partition) ----
    int ks = 0, ke = 0;
    #pragma unroll
    for (int k = 0; k < NIMP; ++k) {
        const float U = __builtin_fmaf((float)k, 0.0625f, 0.03125f) * total;
        ks += (U < Bc);
        ke += (U < Bc1);
    }

    // boundary-neighbor weights for the flip bands
    float wprevB = __shfl_up(aw[15], 1);
    if (sub == 0) wprevB = 0.0f;           // j=0: conservative (matches r7)
    const float wnextB = __shfl_down(aw[0], 1);  // sub3: garbage, provably unused

    // ---- merge-emission over this lane's intervals ----
    int k = ks;
    float Cprev = Bc;
    float U = __builtin_fmaf((float)k, 0.0625f, 0.03125f) * total;
    #pragma unroll
    for (int i = 0; i < 16; ++i) {
        const float w  = aw[i];
        const float Pn = Cprev + w;
        while (k < ke && U < Pn) {
            const float wprev = (i == 0)  ? wprevB : aw[i-1];
            const float wnext = (i == 15) ? wnextB : aw[i+1];
            flag |= (((U - Cprev) < bandU) & (wprev < bandW));
            flag |= (((Pn - U) < bandU) & (wnext < bandW));
            flag |= (w < bandW);
            const float tt = (U - Cprev) * rcp_nr(w);
            out[(size_t)ray * NIMP + k] = __builtin_fmaf(tt, z[i+1] - z[i], z[i]);
            ++k;
            U = __builtin_fmaf((float)k, 0.0625f, 0.03125f) * total;
        }
        Cprev = Pn;
    }
    while (k < ke) {                        // ulp-crack stragglers -> f64 redo
        flag = 1;
        out[(size_t)ray * NIMP + k] = (sub == 3) ? z[15] : z[16];
        ++k;
    }

    // ---- per-ray flag reduce + list append ----
    int fl = flag;
    fl |= __shfl_xor(fl, 1);
    fl |= __shfl_xor(fl, 2);
    if (sub == 0 && fl) {
        const unsigned idx = atomicAdd(ctr, 1u);
        if (idx < cap) list[idx] = (unsigned)ray;
    }
}

// ============================================================================
// Kernel 2: validated r4/r7 f64 wave-per-ray redo over the flagged-ray list.
// ============================================================================
__global__ __launch_bounds__(256) void neus_redo_kernel(
    const float* __restrict__ rays_o,
    const float* __restrict__ rays_d,
    const float* __restrict__ z_vals,
    const float* __restrict__ sdf,
    const float* __restrict__ inv_s,
    float* __restrict__ out,
    const unsigned* __restrict__ ctr,
    const unsigned* __restrict__ list,
    unsigned cap, int forceAll, int B, int n_imp, double u0, double du)
{
    const int lane = threadIdx.x & 63;
    const int wv   = blockIdx.x * 4 + (threadIdx.x >> 6);
    unsigned count = 0; bool over = true;
    if (!forceAll) {
        count = *ctr;
        over  = count > cap;
    }
    const unsigned nwork = over ? (unsigned)B : count;

    for (unsigned i = wv; i < nwork; i += 1024) {
        const int ray = over ? (int)i : (int)list[i];

        const double z = (double)z_vals[(size_t)ray * 64 + lane];
        const double s = (double)sdf   [(size_t)ray * 64 + lane];
        double isv = 0.0;
        if (lane < 63) isv = (double)inv_s[(size_t)ray * 63 + lane];

        const double ox = (double)rays_o[(size_t)ray*3+0];
        const double oy = (double)rays_o[(size_t)ray*3+1];
        const double oz = (double)rays_o[(size_t)ray*3+2];
        const double dx = (double)rays_d[(size_t)ray*3+0];
        const double dy = (double)rays_d[(size_t)ray*3+1];
        const double dz = (double)rays_d[(size_t)ray*3+2];

        const double px = ox + dx*z, py = oy + dy*z, pz = oz + dz*z;
        const double inner = (fabs(px) <= SIDE && fabs(py) <= SIDE && fabs(pz) <= SIDE) ? 1.0 : 0.0;

        const double next_s  = __shfl_down(s, 1);
        const double next_z  = __shfl_down(z, 1);
        const double inner_n = __shfl_down(inner, 1);

        const double inside = ((inner > 0.5) || (inner_n > 0.5)) ? 1.0 : 0.0;
        const double mid    = 0.5 * (s + next_s);
        const double cv0    = (next_s - s) / (next_z - z + 1e-5);
        double prevc = __shfl_up(cv0, 1);
        if (lane == 0) prevc = 0.0;
        double cv = fmin(prevc, cv0);
        cv = fmin(fmax(cv, -1000.0), 0.0) * inside;
        const double dist = next_z - z;

        const double arg_p = (mid - cv * dist * 0.5) * isv;
        const double arg_n = (mid + cv * dist * 0.5) * isv;
        const double a = exp_fast(fmin(fmax(-arg_p, -350.0), 350.0));
        const double b = exp_fast(fmin(fmax(-arg_n, -350.0), 350.0));
        const double P = (1.0 + a) * (1.0 + b);
        const double alpha = (__builtin_fma(1e-5, P, b - a)) /
                             (__builtin_fma(1e-5, P, 1.0 + b));

        double g = (lane < 63) ? (1.0 - alpha + 1e-7) : 1.0;
        double p = g;
        #pragma unroll
        for (int off = 1; off < 64; off <<= 1) {
            double tmp = __shfl_up(p, off);
            if (lane >= off) p *= tmp;
        }
        double trans = __shfl_up(p, 1);
        if (lane == 0) trans = 1.0;

        const double w = (lane < 63) ? (alpha * trans + 1e-5) : 0.0;

        double sc = w;
        #pragma unroll
        for (int off = 1; off < 64; off <<= 1) {
            double tmp = __shfl_up(sc, off);
            if (lane >= off) sc += tmp;
        }
        const double total = __shfl(sc, 63);
        const double excl  = sc - w;
        const double cdf   = excl / total;

        const double u = u0 + du * (double)lane;
        int lo = 0, hi = 64;
        #pragma unroll
        for (int it = 0; it < 7; ++it) {
            const int m  = (lo + hi) >> 1;
            const double cm = __shfl(cdf, m);
            if (lo < hi) {
                if (cm <= u) lo = m + 1; else hi = m;
            }
        }
        const int ind   = lo;
        const int below = max(ind - 1, 0);
        const int above = min(ind, 63);

        const double cb = __shfl(cdf, below);
        const double ca = __shfl(cdf, above);
        const double bb = __shfl(z, below);
        const double ba = __shfl(z, above);

        double denom = ca - cb;
        denom = (denom < 1e-5) ? 1.0 : denom;
        const double tt  = (u - cb) / denom;
        const double r2  = bb + tt * (ba - bb);

        if (lane < n_imp) out[(size_t)ray * n_imp + lane] = (float)r2;
    }
}

extern "C" void kernel_launch(void* const* d_in, const int* in_sizes, int n_in,
                              void* d_out, int out_size, void* d_ws, size_t ws_size,
                              hipStream_t stream) {
    const float* rays_o = (const float*)d_in[0];
    const float* rays_d = (const float*)d_in[1];
    const float* z_vals = (const float*)d_in[2];
    const float* sdf    = (const float*)d_in[3];
    const float* inv_s  = (const float*)d_in[4];
    float* out = (float*)d_out;

    const int B = in_sizes[0] / 3;          // 131072
    const int n = out_size / B;             // n_importance = 16
    const double u0 = 0.5 / (double)n;
    const double du = (n > 1) ? ((1.0 - 1.0 / (double)n) / (double)(n - 1)) : 0.0;

    unsigned* ctr  = (unsigned*)d_ws;
    unsigned* list = (unsigned*)d_ws + 4;

    if (n == NIMP && ws_size >= 64) {
        const unsigned cap = (unsigned)((ws_size - 16) / 4);
        hipMemsetAsync(d_ws, 0, 16, stream);
        const int threads = B * 4;
        neus_fast_kernel<<<(threads + 255) / 256, 256, 0, stream>>>(
            rays_o, rays_d, z_vals, sdf, inv_s, out, ctr, list, cap, B);
        neus_redo_kernel<<<256, 256, 0, stream>>>(
            rays_o, rays_d, z_vals, sdf, inv_s, out, ctr, list, cap, 0, B, n, u0, du);
    } else {
        // generic fallback: full f64 redo over all rays (validated r4 path)
        neus_redo_kernel<<<256, 256, 0, stream>>>(
            rays_o, rays_d, z_vals, sdf, inv_s, out, ctr, list, 0u, 1, B, n, u0, du);
    }
}

// Round 12
// 75.072 us; speedup vs baseline: 1.0274x; 1.0274x over previous
//
#include <hip/hip_runtime.h>
#include <math.h>

#define SIDE 0.6
#define NIMP 16

// ---------- fast f64 exp, |x| <= 350, rel err ~1e-15 (validated r3/r4) ----------
__device__ __forceinline__ double exp_fast(double x) {
    const double INVLN2 = 1.44269504088896338700e+00;
    const double LN2HI  = 6.93147180369123816490e-01;
    const double LN2LO  = 1.90821492927058770002e-10;
    const double kd = __builtin_rint(x * INVLN2);
    const int    k  = (int)kd;
    double r = __builtin_fma(-kd, LN2HI, x);
    r        = __builtin_fma(-kd, LN2LO, r);
    double p =               2.08767569878681e-09;
    p = __builtin_fma(p, r,  2.50521083854417e-08);
    p = __builtin_fma(p, r,  2.75573192239859e-07);
    p = __builtin_fma(p, r,  2.75573192239859e-06);
    p = __builtin_fma(p, r,  2.48015873015873e-05);
    p = __builtin_fma(p, r,  1.98412698412698e-04);
    p = __builtin_fma(p, r,  1.38888888888889e-03);
    p = __builtin_fma(p, r,  8.33333333333333e-03);
    p = __builtin_fma(p, r,  4.16666666666667e-02);
    p = __builtin_fma(p, r,  1.66666666666667e-01);
    p = __builtin_fma(p, r,  5.00000000000000e-01);
    p = __builtin_fma(p, r,  1.0);
    p = __builtin_fma(p, r,  1.0);
    const long long bits = (long long)(1023 + k) << 52;
    return p * __longlong_as_double(bits);
}

// ---------- fast f32 exp, |x| <= 40, rel err ~2e-7 (validated r5/r7/r8/r9) ----------
__device__ __forceinline__ float exp_fast_f(float x) {
    const float kd = rintf(x * 1.44269504f);
    const int   k  = (int)kd;
    float r = __builtin_fmaf(-kd, 0.693359375f, x);
    r       = __builtin_fmaf(kd, 2.12194440e-4f, r);
    float p =                1.98412698e-4f;
    p = __builtin_fmaf(p, r, 1.38888889e-3f);
    p = __builtin_fmaf(p, r, 8.33333333e-3f);
    p = __builtin_fmaf(p, r, 4.16666667e-2f);
    p = __builtin_fmaf(p, r, 1.66666667e-1f);
    p = __builtin_fmaf(p, r, 5.00000000e-1f);
    p = __builtin_fmaf(p, r, 1.0f);
    p = __builtin_fmaf(p, r, 1.0f);
    return p * __int_as_float((127 + k) << 23);
}

#if __has_builtin(__builtin_amdgcn_rcpf)
__device__ __forceinline__ float rcp_nr(float x) {   // ~0.5 ulp: v_rcp + 1 NR
    float r = __builtin_amdgcn_rcpf(x);
    return __builtin_fmaf(__builtin_fmaf(-x, r, 1.0f), r, r);
}
#else
__device__ __forceinline__ float rcp_nr(float x) { return 1.0f / x; }
#endif

// ============================================================================
// Fast kernel: 16 lanes per ray, 4 intervals per lane, SINGLE pass.
// r9's validated scheme with per-thread state shrunk 82 -> 22 array values
// (z[5],s[5],iv[4],aw[4],g[4]) so it fits the 64-VGPR allocation with ZERO
// spill (r9-r11: compiler refuses >64 VGPR; spills were the bottleneck).
// Canonical broadcast loops (identical op order in all 16 lanes) make the
// emission partition boundaries bitwise-identical across lanes -> gap-free.
// Flip-risk bands unchanged (box 1e-5, thin-bin 4e-3, near-boundary 4e-5).
// ============================================================================
__global__ __launch_bounds__(256) void neus_fast_kernel(
    const float* __restrict__ rays_o,
    const float* __restrict__ rays_d,
    const float* __restrict__ z_vals,
    const float* __restrict__ sdf,
    const float* __restrict__ inv_s,
    float* __restrict__ out,
    unsigned* __restrict__ ctr,
    unsigned* __restrict__ list,
    unsigned cap, int B)
{
    const int tid  = blockIdx.x * 256 + threadIdx.x;
    const int ray  = tid >> 4;          // 16 lanes per ray
    const int sub  = tid & 15;
    if (ray >= B) return;               // whole 16-lane group exits together

    const int lane = threadIdx.x & 63;
    const int gb   = lane & ~15;        // base lane of this ray's group

    const float* zp = z_vals + (size_t)ray * 64 + sub * 4;
    const float* sp = sdf    + (size_t)ray * 64 + sub * 4;
    const float* ip = inv_s  + (size_t)ray * 63 + sub * 4;

    const float ox = rays_o[(size_t)ray*3+0];
    const float oy = rays_o[(size_t)ray*3+1];
    const float oz = rays_o[(size_t)ray*3+2];
    const float dx = rays_d[(size_t)ray*3+0];
    const float dy = rays_d[(size_t)ray*3+1];
    const float dz = rays_d[(size_t)ray*3+2];

    // ---- loads: one float4 per lane (16B/lane, fully coalesced) ----
    float z[5], s[5];
    {
        const float4 a = *reinterpret_cast<const float4*>(zp);
        const float4 b = *reinterpret_cast<const float4*>(sp);
        z[0]=a.x; z[1]=a.y; z[2]=a.z; z[3]=a.w;
        s[0]=b.x; s[1]=b.y; s[2]=b.z; s[3]=b.w;
    }
    z[4] = __shfl_down(z[0], 1);    // next lane's first elem (sub15: dead)
    s[4] = __shfl_down(s[0], 1);

    float iv[4];
    iv[0] = ip[0]; iv[1] = ip[1]; iv[2] = ip[2];
    iv[3] = (sub < 15) ? ip[3] : 0.0f;   // global interval 63 doesn't exist

    // ---- inside-box bits + box flip band (each elem evaluated once) ----
    int flag = 0;
    unsigned m = 0;
    #pragma unroll
    for (int i = 0; i < 4; ++i) {
        const float px = __builtin_fmaf(dx, z[i], ox);
        const float py = __builtin_fmaf(dy, z[i], oy);
        const float pz = __builtin_fmaf(dz, z[i], oz);
        const float ax = fabsf(px), ay = fabsf(py), az = fabsf(pz);
        if (ax <= 0.6f && ay <= 0.6f && az <= 0.6f) m |= (1u << i);
        flag |= (fabsf(ax-0.6f) < 1e-5f) | (fabsf(ay-0.6f) < 1e-5f) |
                (fabsf(az-0.6f) < 1e-5f);
    }
    m |= (__shfl_down(m, 1) & 1u) << 4;  // boundary inner bit (sub15: dead)

    // ---- prev_cos carry across lanes ----
    const float cv0_last = (s[4]-s[3]) * rcp_nr(z[4]-z[3] + 1e-5f);
    float prevc = __shfl_up(cv0_last, 1);
    if (sub == 0) prevc = 0.0f;

    // ---- per-interval alpha, g (aw holds alpha for now) ----
    float aw[4], g[4];
    float Gloc = 1.0f;
    #pragma unroll
    for (int i = 0; i < 4; ++i) {
        const float cv0 = (s[i+1]-s[i]) * rcp_nr(z[i+1]-z[i] + 1e-5f);
        float cv = fminf(prevc, cv0);
        prevc = cv0;
        const float inside = ((m >> i) & 3u) ? 1.0f : 0.0f;
        cv = fminf(fmaxf(cv, -1000.f), 0.f) * inside;
        const float mid = 0.5f * (s[i] + s[i+1]);
        const float dzz = z[i+1] - z[i];
        const float q2  = cv * (dzz * 0.5f);
        const float apv = (mid - q2) * iv[i];
        const float anv = (mid + q2) * iv[i];
        const float ea = exp_fast_f(fminf(fmaxf(-apv, -40.f), 40.f));
        const float eb = exp_fast_f(fminf(fmaxf(-anv, -40.f), 40.f));
        const float onea = 1.f + ea;
        const float Pp  = onea * (1.f + eb);
        const float Nn  = __builtin_fmaf(1e-5f, Pp, eb - ea);
        const float Dd  = __builtin_fmaf(1e-5f, Pp, 1.f + eb);
        const float invD = rcp_nr(Dd);
        float al = Nn * invD;
        float gg = __builtin_fmaf(onea, invD, 1e-7f);
        if (i == 3 && sub == 15) { al = 0.f; gg = 1.f; }   // dead interval 63
        aw[i] = al; g[i] = gg;
        Gloc *= gg;
    }

    // ---- T0: canonical product scan (identical op order in all lanes) ----
    float T0 = 1.0f, Pr = 1.0f;
    #pragma unroll
    for (int q = 0; q < 16; ++q) {
        const float Gm = __shfl(Gloc, gb + q);
        if (q == sub) T0 = Pr;
        Pr *= Gm;
    }

    // ---- weights + local sum ----
    float Tr = T0, Sloc = 0.0f;
    #pragma unroll
    for (int i = 0; i < 4; ++i) {
        float w = __builtin_fmaf(aw[i], Tr, 1e-5f);
        if (i == 3 && sub == 15) w = 0.0f;
        Tr *= g[i];
        Sloc += w;
        aw[i] = w;                       // aw now holds weights
    }

    // ---- canonical boundaries: identical running sum in all lanes ----
    float Bc = 0.0f, Bc1 = 0.0f, run = 0.0f;
    #pragma unroll
    for (int q = 0; q < 16; ++q) {
        const float Sm = __shfl(Sloc, gb + q);
        if (q == sub) Bc = run;
        run += Sm;
        if (q == sub) Bc1 = run;
    }
    const float total = run;
    const float bandU = 4e-5f * total;
    const float bandW = 4e-3f * total;

    // ---- k-range owned by this lane ----
    int ks = 0, ke = 0;
    #pragma unroll
    for (int k = 0; k < NIMP; ++k) {
        const float U = __builtin_fmaf((float)k, 0.0625f, 0.03125f) * total;
        ks += (U < Bc);
        ke += (U < Bc1);
    }

    // boundary-neighbor weights for the flip bands
    float wprevB = __shfl_up(aw[3], 1);
    if (sub == 0) wprevB = 0.0f;              // j=0: conservative (as r9)
    const float wnextB = __shfl_down(aw[0], 1);  // sub15: dead-interval only

    // ---- merge-emission over this lane's 4 intervals ----
    int k = ks;
    float Cprev = Bc;
    float U = __builtin_fmaf((float)k, 0.0625f, 0.03125f) * total;
    #pragma unroll
    for (int i = 0; i < 4; ++i) {
        const float w  = aw[i];
        const float Pn = Cprev + w;
        while (k < ke && U < Pn) {
            const float wprev = (i == 0) ? wprevB : aw[i-1];
            const float wnext = (i == 3) ? wnextB : aw[i+1];
            flag |= (((U - Cprev) < bandU) & (wprev < bandW));
            flag |= (((Pn - U) < bandU) & (wnext < bandW));
            flag |= (w < bandW);
            const float tt = (U - Cprev) * rcp_nr(w);
            out[(size_t)ray * NIMP + k] = __builtin_fmaf(tt, z[i+1] - z[i], z[i]);
            ++k;
            U = __builtin_fmaf((float)k, 0.0625f, 0.03125f) * total;
        }
        Cprev = Pn;
    }
    while (k < ke) {                     // ulp-crack stragglers -> f64 redo
        flag = 1;
        out[(size_t)ray * NIMP + k] = (sub == 15) ? z[3] : z[4];
        ++k;
    }

    // ---- per-ray flag reduce (16 lanes) + list append ----
    int fl = flag;
    fl |= __shfl_xor(fl, 1);
    fl |= __shfl_xor(fl, 2);
    fl |= __shfl_xor(fl, 4);
    fl |= __shfl_xor(fl, 8);
    if (sub == 0 && fl) {
        const unsigned idx = atomicAdd(ctr, 1u);
        if (idx < cap) list[idx] = (unsigned)ray;
    }
}

// ============================================================================
// Kernel 2: validated r4/r7 f64 wave-per-ray redo over the flagged-ray list.
// ============================================================================
__global__ __launch_bounds__(256) void neus_redo_kernel(
    const float* __restrict__ rays_o,
    const float* __restrict__ rays_d,
    const float* __restrict__ z_vals,
    const float* __restrict__ sdf,
    const float* __restrict__ inv_s,
    float* __restrict__ out,
    const unsigned* __restrict__ ctr,
    const unsigned* __restrict__ list,
    unsigned cap, int forceAll, int B, int n_imp, double u0, double du)
{
    const int lane = threadIdx.x & 63;
    const int wv   = blockIdx.x * 4 + (threadIdx.x >> 6);
    unsigned count = 0; bool over = true;
    if (!forceAll) {
        count = *ctr;
        over  = count > cap;
    }
    const unsigned nwork = over ? (unsigned)B : count;

    for (unsigned i = wv; i < nwork; i += 1024) {
        const int ray = over ? (int)i : (int)list[i];

        const double z = (double)z_vals[(size_t)ray * 64 + lane];
        const double s = (double)sdf   [(size_t)ray * 64 + lane];
        double isv = 0.0;
        if (lane < 63) isv = (double)inv_s[(size_t)ray * 63 + lane];

        const double ox = (double)rays_o[(size_t)ray*3+0];
        const double oy = (double)rays_o[(size_t)ray*3+1];
        const double oz = (double)rays_o[(size_t)ray*3+2];
        const double dx = (double)rays_d[(size_t)ray*3+0];
        const double dy = (double)rays_d[(size_t)ray*3+1];
        const double dz = (double)rays_d[(size_t)ray*3+2];

        const double px = ox + dx*z, py = oy + dy*z, pz = oz + dz*z;
        const double inner = (fabs(px) <= SIDE && fabs(py) <= SIDE && fabs(pz) <= SIDE) ? 1.0 : 0.0;

        const double next_s  = __shfl_down(s, 1);
        const double next_z  = __shfl_down(z, 1);
        const double inner_n = __shfl_down(inner, 1);

        const double inside = ((inner > 0.5) || (inner_n > 0.5)) ? 1.0 : 0.0;
        const double mid    = 0.5 * (s + next_s);
        const double cv0    = (next_s - s) / (next_z - z + 1e-5);
        double prevc = __shfl_up(cv0, 1);
        if (lane == 0) prevc = 0.0;
        double cv = fmin(prevc, cv0);
        cv = fmin(fmax(cv, -1000.0), 0.0) * inside;
        const double dist = next_z - z;

        const double arg_p = (mid - cv * dist * 0.5) * isv;
        const double arg_n = (mid + cv * dist * 0.5) * isv;
        const double a = exp_fast(fmin(fmax(-arg_p, -350.0), 350.0));
        const double b = exp_fast(fmin(fmax(-arg_n, -350.0), 350.0));
        const double P = (1.0 + a) * (1.0 + b);
        const double alpha = (__builtin_fma(1e-5, P, b - a)) /
                             (__builtin_fma(1e-5, P, 1.0 + b));

        double g = (lane < 63) ? (1.0 - alpha + 1e-7) : 1.0;
        double p = g;
        #pragma unroll
        for (int off = 1; off < 64; off <<= 1) {
            double tmp = __shfl_up(p, off);
            if (lane >= off) p *= tmp;
        }
        double trans = __shfl_up(p, 1);
        if (lane == 0) trans = 1.0;

        const double w = (lane < 63) ? (alpha * trans + 1e-5) : 0.0;

        double sc = w;
        #pragma unroll
        for (int off = 1; off < 64; off <<= 1) {
            double tmp = __shfl_up(sc, off);
            if (lane >= off) sc += tmp;
        }
        const double total = __shfl(sc, 63);
        const double excl  = sc - w;
        const double cdf   = excl / total;

        const double u = u0 + du * (double)lane;
        int lo = 0, hi = 64;
        #pragma unroll
        for (int it = 0; it < 7; ++it) {
            const int m  = (lo + hi) >> 1;
            const double cm = __shfl(cdf, m);
            if (lo < hi) {
                if (cm <= u) lo = m + 1; else hi = m;
            }
        }
        const int ind   = lo;
        const int below = max(ind - 1, 0);
        const int above = min(ind, 63);

        const double cb = __shfl(cdf, below);
        const double ca = __shfl(cdf, above);
        const double bb = __shfl(z, below);
        const double ba = __shfl(z, above);

        double denom = ca - cb;
        denom = (denom < 1e-5) ? 1.0 : denom;
        const double tt  = (u - cb) / denom;
        const double r2  = bb + tt * (ba - bb);

        if (lane < n_imp) out[(size_t)ray * n_imp + lane] = (float)r2;
    }
}

extern "C" void kernel_launch(void* const* d_in, const int* in_sizes, int n_in,
                              void* d_out, int out_size, void* d_ws, size_t ws_size,
                              hipStream_t stream) {
    const float* rays_o = (const float*)d_in[0];
    const float* rays_d = (const float*)d_in[1];
    const float* z_vals = (const float*)d_in[2];
    const float* sdf    = (const float*)d_in[3];
    const float* inv_s  = (const float*)d_in[4];
    float* out = (float*)d_out;

    const int B = in_sizes[0] / 3;          // 131072
    const int n = out_size / B;             // n_importance = 16
    const double u0 = 0.5 / (double)n;
    const double du = (n > 1) ? ((1.0 - 1.0 / (double)n) / (double)(n - 1)) : 0.0;

    unsigned* ctr  = (unsigned*)d_ws;
    unsigned* list = (unsigned*)d_ws + 4;

    if (n == NIMP && ws_size >= 64) {
        const unsigned cap = (unsigned)((ws_size - 16) / 4);
        hipMemsetAsync(d_ws, 0, 16, stream);
        const long long threads = (long long)B * 16;
        neus_fast_kernel<<<(int)((threads + 255) / 256), 256, 0, stream>>>(
            rays_o, rays_d, z_vals, sdf, inv_s, out, ctr, list, cap, B);
        neus_redo_kernel<<<256, 256, 0, stream>>>(
            rays_o, rays_d, z_vals, sdf, inv_s, out, ctr, list, cap, 0, B, n, u0, du);
    } else {
        // generic fallback: full f64 redo over all rays (validated r4 path)
        neus_redo_kernel<<<256, 256, 0, stream>>>(
            rays_o, rays_d, z_vals, sdf, inv_s, out, ctr, list, 0u, 1, B, n, u0, du);
    }
}

// Round 13
// 45.658 us; speedup vs baseline: 1.6892x; 1.6442x over previous
//
#include <hip/hip_runtime.h>
#include <math.h>

#define SIDE 0.6
#define NIMP 16

// ---------- fast f64 exp, |x| <= 350, rel err ~1e-15 (validated r3/r4) ----------
__device__ __forceinline__ double exp_fast(double x) {
    const double INVLN2 = 1.44269504088896338700e+00;
    const double LN2HI  = 6.93147180369123816490e-01;
    const double LN2LO  = 1.90821492927058770002e-10;
    const double kd = __builtin_rint(x * INVLN2);
    const int    k  = (int)kd;
    double r = __builtin_fma(-kd, LN2HI, x);
    r        = __builtin_fma(-kd, LN2LO, r);
    double p =               2.08767569878681e-09;
    p = __builtin_fma(p, r,  2.50521083854417e-08);
    p = __builtin_fma(p, r,  2.75573192239859e-07);
    p = __builtin_fma(p, r,  2.75573192239859e-06);
    p = __builtin_fma(p, r,  2.48015873015873e-05);
    p = __builtin_fma(p, r,  1.98412698412698e-04);
    p = __builtin_fma(p, r,  1.38888888888889e-03);
    p = __builtin_fma(p, r,  8.33333333333333e-03);
    p = __builtin_fma(p, r,  4.16666666666667e-02);
    p = __builtin_fma(p, r,  1.66666666666667e-01);
    p = __builtin_fma(p, r,  5.00000000000000e-01);
    p = __builtin_fma(p, r,  1.0);
    p = __builtin_fma(p, r,  1.0);
    const long long bits = (long long)(1023 + k) << 52;
    return p * __longlong_as_double(bits);
}

// ---------- fast f32 exp, |x| <= 40, rel err ~2e-7 (validated r5-r12) ----------
__device__ __forceinline__ float exp_fast_f(float x) {
    const float kd = rintf(x * 1.44269504f);
    const int   k  = (int)kd;
    float r = __builtin_fmaf(-kd, 0.693359375f, x);
    r       = __builtin_fmaf(kd, 2.12194440e-4f, r);
    float p =                1.98412698e-4f;
    p = __builtin_fmaf(p, r, 1.38888889e-3f);
    p = __builtin_fmaf(p, r, 8.33333333e-3f);
    p = __builtin_fmaf(p, r, 4.16666667e-2f);
    p = __builtin_fmaf(p, r, 1.66666667e-1f);
    p = __builtin_fmaf(p, r, 5.00000000e-1f);
    p = __builtin_fmaf(p, r, 1.0f);
    p = __builtin_fmaf(p, r, 1.0f);
    return p * __int_as_float((127 + k) << 23);
}

#if __has_builtin(__builtin_amdgcn_rcpf)
__device__ __forceinline__ float rcp_nr(float x) {   // ~0.5 ulp: v_rcp + 1 NR
    float r = __builtin_amdgcn_rcpf(x);
    return __builtin_fmaf(__builtin_fmaf(-x, r, 1.0f), r, r);
}
#else
__device__ __forceinline__ float rcp_nr(float x) { return 1.0f / x; }
#endif

// ============================================================================
// Fast kernel: 16 lanes per ray, 4 intervals per lane, lane-per-sample
// emission (NIMP == 16 == lanes/ray). Straight-line code only: no divergent
// while-loops, no k-range scan, no canonical 16-step loops (r12 postmortem:
// those were ~80% of the 2350 instr/wave). Hierarchical canonical prefix
// (4x4, left-assoc) is provably monotone -> 4-step binary search per sample;
// every sample k is written exactly once by lane k (no gaps, no stragglers).
// Flip-risk bands unchanged (box 1e-5, thin-bin 4e-3, near-boundary 4e-5);
// flagged rays -> validated f64 redo kernel.
// ============================================================================
__global__ __launch_bounds__(256) void neus_fast_kernel(
    const float* __restrict__ rays_o,
    const float* __restrict__ rays_d,
    const float* __restrict__ z_vals,
    const float* __restrict__ sdf,
    const float* __restrict__ inv_s,
    float* __restrict__ out,
    unsigned* __restrict__ ctr,
    unsigned* __restrict__ list,
    unsigned cap, int B)
{
    const int tid  = blockIdx.x * 256 + threadIdx.x;
    const int ray  = tid >> 4;          // 16 lanes per ray
    const int sub  = tid & 15;
    if (ray >= B) return;               // whole 16-lane group exits together

    const int lane = threadIdx.x & 63;
    const int gb   = lane & ~15;        // ray-group base lane
    const int g4   = lane & ~3;         // 4-lane subgroup base
    const int s4   = sub & 3;
    const int gq   = sub >> 2;

    const float* zp = z_vals + (size_t)ray * 64 + sub * 4;
    const float* sp = sdf    + (size_t)ray * 64 + sub * 4;
    const float* ip = inv_s  + (size_t)ray * 63 + sub * 4;

    const float ox = rays_o[(size_t)ray*3+0];
    const float oy = rays_o[(size_t)ray*3+1];
    const float oz = rays_o[(size_t)ray*3+2];
    const float dx = rays_d[(size_t)ray*3+0];
    const float dy = rays_d[(size_t)ray*3+1];
    const float dz = rays_d[(size_t)ray*3+2];

    // ---- loads: one float4 per lane (16B/lane, coalesced) ----
    float z[5], s[5];
    {
        const float4 a = *reinterpret_cast<const float4*>(zp);
        const float4 b = *reinterpret_cast<const float4*>(sp);
        z[0]=a.x; z[1]=a.y; z[2]=a.z; z[3]=a.w;
        s[0]=b.x; s[1]=b.y; s[2]=b.z; s[3]=b.w;
    }
    z[4] = __shfl_down(z[0], 1);    // next lane's first elem (sub15: dead use)
    s[4] = __shfl_down(s[0], 1);

    float iv[4];
    iv[0] = ip[0]; iv[1] = ip[1]; iv[2] = ip[2];
    iv[3] = (sub < 15) ? ip[3] : 0.0f;   // global interval 63 doesn't exist

    // ---- inside-box bits + box flip band ----
    int flag = 0;
    unsigned m = 0;
    #pragma unroll
    for (int i = 0; i < 4; ++i) {
        const float px = __builtin_fmaf(dx, z[i], ox);
        const float py = __builtin_fmaf(dy, z[i], oy);
        const float pz = __builtin_fmaf(dz, z[i], oz);
        const float ax = fabsf(px), ay = fabsf(py), az = fabsf(pz);
        if (ax <= 0.6f && ay <= 0.6f && az <= 0.6f) m |= (1u << i);
        const float d3 = fminf(fminf(fabsf(ax-0.6f), fabsf(ay-0.6f)),
                               fabsf(az-0.6f));
        flag |= (d3 < 1e-5f);
    }
    m |= (__shfl_down(m, 1) & 1u) << 4;  // boundary inner bit (sub15: dead)

    // ---- prev_cos carry across lanes ----
    const float cv0_last = (s[4]-s[3]) * rcp_nr(z[4]-z[3] + 1e-5f);
    float prevc = __shfl_up(cv0_last, 1);
    if (sub == 0) prevc = 0.0f;

    // ---- per-interval alpha, g (w[] holds alpha for now) ----
    float w[4], g[4];
    float Gloc = 1.0f;
    #pragma unroll
    for (int i = 0; i < 4; ++i) {
        const float cv0 = (s[i+1]-s[i]) * rcp_nr(z[i+1]-z[i] + 1e-5f);
        float cv = fminf(prevc, cv0);
        prevc = cv0;
        const float inside = ((m >> i) & 3u) ? 1.0f : 0.0f;
        cv = fminf(fmaxf(cv, -1000.f), 0.f) * inside;
        const float mid = 0.5f * (s[i] + s[i+1]);
        const float dzz = z[i+1] - z[i];
        const float q2  = cv * (dzz * 0.5f);
        const float apv = (mid - q2) * iv[i];
        const float anv = (mid + q2) * iv[i];
        const float ea = exp_fast_f(fminf(fmaxf(-apv, -40.f), 40.f));
        const float eb = exp_fast_f(fminf(fmaxf(-anv, -40.f), 40.f));
        const float onea = 1.f + ea;
        const float Pp  = onea * (1.f + eb);
        const float Nn  = __builtin_fmaf(1e-5f, Pp, eb - ea);
        const float Dd  = __builtin_fmaf(1e-5f, Pp, 1.f + eb);
        const float invD = rcp_nr(Dd);
        float al = Nn * invD;
        float gg = __builtin_fmaf(onea, invD, 1e-7f);
        if (i == 3 && sub == 15) { al = 0.f; gg = 1.f; }   // dead interval 63
        w[i] = al; g[i] = gg;
        Gloc *= gg;
    }

    // ---- T0: hierarchical product (4x4); any consistent association OK ----
    {
        const float Ga = __shfl(Gloc, g4+0);
        const float Gb = __shfl(Gloc, g4+1);
        const float Gc = __shfl(Gloc, g4+2);
        const float Gd = __shfl(Gloc, g4+3);
        float Tw = 1.0f;
        if (s4 > 0) Tw = Ga;
        if (s4 > 1) Tw *= Gb;
        if (s4 > 2) Tw *= Gc;
        const float Gg = ((Ga*Gb)*Gc)*Gd;
        const float PA = __shfl(Gg, gb+0);
        const float PB = __shfl(Gg, gb+4);
        const float PC = __shfl(Gg, gb+8);
        float Pp = 1.0f;
        if (gq > 0) Pp = PA;
        if (gq > 1) Pp *= PB;
        if (gq > 2) Pp *= PC;
        Gloc = Pp * Tw;                 // reuse Gloc as T0
    }

    // ---- weights + local sum ----
    float Tr = Gloc, Sloc = 0.0f;
    #pragma unroll
    for (int i = 0; i < 4; ++i) {
        float ww = __builtin_fmaf(w[i], Tr, 1e-5f);
        if (i == 3 && sub == 15) ww = 0.0f;
        Tr *= g[i];
        Sloc += ww;
        w[i] = ww;                       // w now holds weights
    }

    // ---- Bc: hierarchical canonical exclusive prefix (monotone) ----
    float Bc, total;
    {
        const float Sa = __shfl(Sloc, g4+0);
        const float Sb = __shfl(Sloc, g4+1);
        const float Sc = __shfl(Sloc, g4+2);
        const float Sd = __shfl(Sloc, g4+3);
        float W = 0.0f;
        if (s4 > 0) W = Sa;
        if (s4 > 1) W += Sb;
        if (s4 > 2) W += Sc;
        const float Gs = ((Sa+Sb)+Sc)+Sd;
        const float GA = __shfl(Gs, gb+0);
        const float GB = __shfl(Gs, gb+4);
        const float GC = __shfl(Gs, gb+8);
        const float GD = __shfl(Gs, gb+12);
        float Pg = 0.0f;
        if (gq > 0) Pg = GA;
        if (gq > 1) Pg += GB;
        if (gq > 2) Pg += GC;
        Bc    = Pg + W;
        total = ((GA+GB)+GC)+GD;
    }
    const float bandU = 4e-5f * total;
    const float bandW = 4e-3f * total;

    // ---- lane-per-sample emission: lane sub owns sample k = sub ----
    const float U = __builtin_fmaf((float)sub, 0.0625f, 0.03125f) * total;

    int own = 0;                         // largest q with Bc_q <= U (Bc_0 = 0)
    { const float t = __shfl(Bc, gb + (own|8)); if (t <= U) own |= 8; }
    { const float t = __shfl(Bc, gb + (own|4)); if (t <= U) own |= 4; }
    { const float t = __shfl(Bc, gb + (own|2)); if (t <= U) own |= 2; }
    { const float t = __shfl(Bc, gb + (own|1)); if (t <= U) own |= 1; }
    const int ol = gb + own;

    const float Cown = __shfl(Bc, ol);
    const float w0 = __shfl(w[0], ol);
    const float w1 = __shfl(w[1], ol);
    const float w2 = __shfl(w[2], ol);
    const float w3 = __shfl(w[3], ol);
    const float za = __shfl(z[0], ol);
    const float zb = __shfl(z[1], ol);
    const float zc = __shfl(z[2], ol);
    const float zd = __shfl(z[3], ol);
    const float ze = __shfl(z[4], ol);
    const float wpB = __shfl(w[3], max(ol-1, 0));   // owner-1 last w (own==0: unused)
    const float wnB = __shfl(w[0], min(ol+1, 63));  // owner+1 first w (j==3 w/ own==15: impossible)

    const float c1 = Cown + w0, c2 = c1 + w1, c3 = c2 + w2;
    const int j = (U >= c1) + (U >= c2) + (U >= c3);   // 0..3
    const float cj  = (j==0)?Cown:(j==1)?c1:(j==2)?c2:c3;
    const float wj  = (j==0)?w0:(j==1)?w1:(j==2)?w2:w3;
    const float zj  = (j==0)?za:(j==1)?zb:(j==2)?zc:zd;
    const float zj1 = (j==0)?zb:(j==1)?zc:(j==2)?zd:ze;
    const float wprev = (j==0)?wpB:(j==1)?w0:(j==2)?w1:w2;
    const float wnext = (j==0)?w1:(j==1)?w2:(j==2)?w3:wnB;

    flag |= (wj < bandW);
    flag |= (((U - cj) < bandU) & (wprev < bandW));
    flag |= (((cj + wj - U) < bandU) & (wnext < bandW));

    const float tt = (U - cj) * rcp_nr(wj);
    out[(size_t)ray * NIMP + sub] = __builtin_fmaf(tt, zj1 - zj, zj);

    // ---- per-ray flag reduce (16 lanes) + list append ----
    int fl = flag;
    fl |= __shfl_xor(fl, 1);
    fl |= __shfl_xor(fl, 2);
    fl |= __shfl_xor(fl, 4);
    fl |= __shfl_xor(fl, 8);
    if (sub == 0 && fl) {
        const unsigned idx = atomicAdd(ctr, 1u);
        if (idx < cap) list[idx] = (unsigned)ray;
    }
}

// ============================================================================
// Kernel 2: validated r4/r7 f64 wave-per-ray redo over the flagged-ray list.
// ============================================================================
__global__ __launch_bounds__(256) void neus_redo_kernel(
    const float* __restrict__ rays_o,
    const float* __restrict__ rays_d,
    const float* __restrict__ z_vals,
    const float* __restrict__ sdf,
    const float* __restrict__ inv_s,
    float* __restrict__ out,
    const unsigned* __restrict__ ctr,
    const unsigned* __restrict__ list,
    unsigned cap, int forceAll, int B, int n_imp, double u0, double du)
{
    const int lane = threadIdx.x & 63;
    const int wv   = blockIdx.x * 4 + (threadIdx.x >> 6);
    unsigned count = 0; bool over = true;
    if (!forceAll) {
        count = *ctr;
        over  = count > cap;
    }
    const unsigned nwork = over ? (unsigned)B : count;

    for (unsigned i = wv; i < nwork; i += 1024) {
        const int ray = over ? (int)i : (int)list[i];

        const double z = (double)z_vals[(size_t)ray * 64 + lane];
        const double s = (double)sdf   [(size_t)ray * 64 + lane];
        double isv = 0.0;
        if (lane < 63) isv = (double)inv_s[(size_t)ray * 63 + lane];

        const double ox = (double)rays_o[(size_t)ray*3+0];
        const double oy = (double)rays_o[(size_t)ray*3+1];
        const double oz = (double)rays_o[(size_t)ray*3+2];
        const double dx = (double)rays_d[(size_t)ray*3+0];
        const double dy = (double)rays_d[(size_t)ray*3+1];
        const double dz = (double)rays_d[(size_t)ray*3+2];

        const double px = ox + dx*z, py = oy + dy*z, pz = oz + dz*z;
        const double inner = (fabs(px) <= SIDE && fabs(py) <= SIDE && fabs(pz) <= SIDE) ? 1.0 : 0.0;

        const double next_s  = __shfl_down(s, 1);
        const double next_z  = __shfl_down(z, 1);
        const double inner_n = __shfl_down(inner, 1);

        const double inside = ((inner > 0.5) || (inner_n > 0.5)) ? 1.0 : 0.0;
        const double mid    = 0.5 * (s + next_s);
        const double cv0    = (next_s - s) / (next_z - z + 1e-5);
        double prevc = __shfl_up(cv0, 1);
        if (lane == 0) prevc = 0.0;
        double cv = fmin(prevc, cv0);
        cv = fmin(fmax(cv, -1000.0), 0.0) * inside;
        const double dist = next_z - z;

        const double arg_p = (mid - cv * dist * 0.5) * isv;
        const double arg_n = (mid + cv * dist * 0.5) * isv;
        const double a = exp_fast(fmin(fmax(-arg_p, -350.0), 350.0));
        const double b = exp_fast(fmin(fmax(-arg_n, -350.0), 350.0));
        const double P = (1.0 + a) * (1.0 + b);
        const double alpha = (__builtin_fma(1e-5, P, b - a)) /
                             (__builtin_fma(1e-5, P, 1.0 + b));

        double g = (lane < 63) ? (1.0 - alpha + 1e-7) : 1.0;
        double p = g;
        #pragma unroll
        for (int off = 1; off < 64; off <<= 1) {
            double tmp = __shfl_up(p, off);
            if (lane >= off) p *= tmp;
        }
        double trans = __shfl_up(p, 1);
        if (lane == 0) trans = 1.0;

        const double w = (lane < 63) ? (alpha * trans + 1e-5) : 0.0;

        double sc = w;
        #pragma unroll
        for (int off = 1; off < 64; off <<= 1) {
            double tmp = __shfl_up(sc, off);
            if (lane >= off) sc += tmp;
        }
        const double total = __shfl(sc, 63);
        const double excl  = sc - w;
        const double cdf   = excl / total;

        const double u = u0 + du * (double)lane;
        int lo = 0, hi = 64;
        #pragma unroll
        for (int it = 0; it < 7; ++it) {
            const int m  = (lo + hi) >> 1;
            const double cm = __shfl(cdf, m);
            if (lo < hi) {
                if (cm <= u) lo = m + 1; else hi = m;
            }
        }
        const int ind   = lo;
        const int below = max(ind - 1, 0);
        const int above = min(ind, 63);

        const double cb = __shfl(cdf, below);
        const double ca = __shfl(cdf, above);
        const double bb = __shfl(z, below);
        const double ba = __shfl(z, above);

        double denom = ca - cb;
        denom = (denom < 1e-5) ? 1.0 : denom;
        const double tt  = (u - cb) / denom;
        const double r2  = bb + tt * (ba - bb);

        if (lane < n_imp) out[(size_t)ray * n_imp + lane] = (float)r2;
    }
}

extern "C" void kernel_launch(void* const* d_in, const int* in_sizes, int n_in,
                              void* d_out, int out_size, void* d_ws, size_t ws_size,
                              hipStream_t stream) {
    const float* rays_o = (const float*)d_in[0];
    const float* rays_d = (const float*)d_in[1];
    const float* z_vals = (const float*)d_in[2];
    const float* sdf    = (const float*)d_in[3];
    const float* inv_s  = (const float*)d_in[4];
    float* out = (float*)d_out;

    const int B = in_sizes[0] / 3;          // 131072
    const int n = out_size / B;             // n_importance = 16
    const double u0 = 0.5 / (double)n;
    const double du = (n > 1) ? ((1.0 - 1.0 / (double)n) / (double)(n - 1)) : 0.0;

    unsigned* ctr  = (unsigned*)d_ws;
    unsigned* list = (unsigned*)d_ws + 4;

    if (n == NIMP && ws_size >= 64) {
        const unsigned cap = (unsigned)((ws_size - 16) / 4);
        hipMemsetAsync(d_ws, 0, 16, stream);
        const long long threads = (long long)B * 16;
        neus_fast_kernel<<<(int)((threads + 255) / 256), 256, 0, stream>>>(
            rays_o, rays_d, z_vals, sdf, inv_s, out, ctr, list, cap, B);
        neus_redo_kernel<<<256, 256, 0, stream>>>(
            rays_o, rays_d, z_vals, sdf, inv_s, out, ctr, list, cap, 0, B, n, u0, du);
    } else {
        // generic fallback: full f64 redo over all rays (validated r4 path)
        neus_redo_kernel<<<256, 256, 0, stream>>>(
            rays_o, rays_d, z_vals, sdf, inv_s, out, ctr, list, 0u, 1, B, n, u0, du);
    }
}

// Round 14
// 35.954 us; speedup vs baseline: 2.1452x; 1.2699x over previous
//
#include <hip/hip_runtime.h>
#include <math.h>

#define SIDE 0.6
#define NIMP 16

// ---------- fast f64 exp, |x| <= 350, rel err ~1e-15 (validated r3/r4) ----------
__device__ __forceinline__ double exp_fast(double x) {
    const double INVLN2 = 1.44269504088896338700e+00;
    const double LN2HI  = 6.93147180369123816490e-01;
    const double LN2LO  = 1.90821492927058770002e-10;
    const double kd = __builtin_rint(x * INVLN2);
    const int    k  = (int)kd;
    double r = __builtin_fma(-kd, LN2HI, x);
    r        = __builtin_fma(-kd, LN2LO, r);
    double p =               2.08767569878681e-09;
    p = __builtin_fma(p, r,  2.50521083854417e-08);
    p = __builtin_fma(p, r,  2.75573192239859e-07);
    p = __builtin_fma(p, r,  2.75573192239859e-06);
    p = __builtin_fma(p, r,  2.48015873015873e-05);
    p = __builtin_fma(p, r,  1.98412698412698e-04);
    p = __builtin_fma(p, r,  1.38888888888889e-03);
    p = __builtin_fma(p, r,  8.33333333333333e-03);
    p = __builtin_fma(p, r,  4.16666666666667e-02);
    p = __builtin_fma(p, r,  1.66666666666667e-01);
    p = __builtin_fma(p, r,  5.00000000000000e-01);
    p = __builtin_fma(p, r,  1.0);
    p = __builtin_fma(p, r,  1.0);
    const long long bits = (long long)(1023 + k) << 52;
    return p * __longlong_as_double(bits);
}

// ---------- fast f32 exp, |x| <= 40, rel err ~2e-7 (validated r5-r13) ----------
__device__ __forceinline__ float exp_fast_f(float x) {
    const float kd = rintf(x * 1.44269504f);
    const int   k  = (int)kd;
    float r = __builtin_fmaf(-kd, 0.693359375f, x);
    r       = __builtin_fmaf(kd, 2.12194440e-4f, r);
    float p =                1.98412698e-4f;
    p = __builtin_fmaf(p, r, 1.38888889e-3f);
    p = __builtin_fmaf(p, r, 8.33333333e-3f);
    p = __builtin_fmaf(p, r, 4.16666667e-2f);
    p = __builtin_fmaf(p, r, 1.66666667e-1f);
    p = __builtin_fmaf(p, r, 5.00000000e-1f);
    p = __builtin_fmaf(p, r, 1.0f);
    p = __builtin_fmaf(p, r, 1.0f);
    return p * __int_as_float((127 + k) << 23);
}

#if __has_builtin(__builtin_amdgcn_rcpf)
__device__ __forceinline__ float rcp_nr(float x) {   // ~0.5 ulp: v_rcp + 1 NR
    float r = __builtin_amdgcn_rcpf(x);
    return __builtin_fmaf(__builtin_fmaf(-x, r, 1.0f), r, r);
}
#else
__device__ __forceinline__ float rcp_nr(float x) { return 1.0f / x; }
#endif

// ============================================================================
// FUSED kernel: r13's validated f32 fast path (16 lanes/ray, 4 intervals/lane,
// lane-per-sample emission) + INLINE f64 redo for flagged rays.
// The flag is reduced over the 16-lane group (uniform) -> group-uniform
// branch re-does its own ray in f64 (reference numerics, r4-validated form),
// reloading inputs from global (L2-hot) so hot-path register pressure stays
// at r13's VGPR=32. No ctr/list/memset/second-dispatch (r13: ~10us overhead).
// ============================================================================
__global__ __launch_bounds__(256) void neus_fused_kernel(
    const float* __restrict__ rays_o,
    const float* __restrict__ rays_d,
    const float* __restrict__ z_vals,
    const float* __restrict__ sdf,
    const float* __restrict__ inv_s,
    float* __restrict__ out,
    int B)
{
    const int tid  = blockIdx.x * 256 + threadIdx.x;
    const int ray  = tid >> 4;          // 16 lanes per ray
    const int sub  = tid & 15;
    if (ray >= B) return;

    const int lane = threadIdx.x & 63;
    const int gb   = lane & ~15;        // ray-group base lane
    const int g4   = lane & ~3;         // 4-lane subgroup base
    const int s4   = sub & 3;
    const int gq   = sub >> 2;

    const float* zp = z_vals + (size_t)ray * 64 + sub * 4;
    const float* sp = sdf    + (size_t)ray * 64 + sub * 4;
    const float* ip = inv_s  + (size_t)ray * 63 + sub * 4;

    const float ox = rays_o[(size_t)ray*3+0];
    const float oy = rays_o[(size_t)ray*3+1];
    const float oz = rays_o[(size_t)ray*3+2];
    const float dx = rays_d[(size_t)ray*3+0];
    const float dy = rays_d[(size_t)ray*3+1];
    const float dz = rays_d[(size_t)ray*3+2];

    // ==================== f32 fast path (r13, verbatim) ====================
    float z[5], s[5];
    {
        const float4 a = *reinterpret_cast<const float4*>(zp);
        const float4 b = *reinterpret_cast<const float4*>(sp);
        z[0]=a.x; z[1]=a.y; z[2]=a.z; z[3]=a.w;
        s[0]=b.x; s[1]=b.y; s[2]=b.z; s[3]=b.w;
    }
    z[4] = __shfl_down(z[0], 1);
    s[4] = __shfl_down(s[0], 1);

    float iv[4];
    iv[0] = ip[0]; iv[1] = ip[1]; iv[2] = ip[2];
    iv[3] = (sub < 15) ? ip[3] : 0.0f;

    int flag = 0;
    unsigned m = 0;
    #pragma unroll
    for (int i = 0; i < 4; ++i) {
        const float px = __builtin_fmaf(dx, z[i], ox);
        const float py = __builtin_fmaf(dy, z[i], oy);
        const float pz = __builtin_fmaf(dz, z[i], oz);
        const float ax = fabsf(px), ay = fabsf(py), az = fabsf(pz);
        if (ax <= 0.6f && ay <= 0.6f && az <= 0.6f) m |= (1u << i);
        const float d3 = fminf(fminf(fabsf(ax-0.6f), fabsf(ay-0.6f)),
                               fabsf(az-0.6f));
        flag |= (d3 < 1e-5f);
    }
    m |= (__shfl_down(m, 1) & 1u) << 4;

    const float cv0_last = (s[4]-s[3]) * rcp_nr(z[4]-z[3] + 1e-5f);
    float prevc = __shfl_up(cv0_last, 1);
    if (sub == 0) prevc = 0.0f;

    float w[4], g[4];
    float Gloc = 1.0f;
    #pragma unroll
    for (int i = 0; i < 4; ++i) {
        const float cv0 = (s[i+1]-s[i]) * rcp_nr(z[i+1]-z[i] + 1e-5f);
        float cv = fminf(prevc, cv0);
        prevc = cv0;
        const float inside = ((m >> i) & 3u) ? 1.0f : 0.0f;
        cv = fminf(fmaxf(cv, -1000.f), 0.f) * inside;
        const float mid = 0.5f * (s[i] + s[i+1]);
        const float dzz = z[i+1] - z[i];
        const float q2  = cv * (dzz * 0.5f);
        const float apv = (mid - q2) * iv[i];
        const float anv = (mid + q2) * iv[i];
        const float ea = exp_fast_f(fminf(fmaxf(-apv, -40.f), 40.f));
        const float eb = exp_fast_f(fminf(fmaxf(-anv, -40.f), 40.f));
        const float onea = 1.f + ea;
        const float Pp  = onea * (1.f + eb);
        const float Nn  = __builtin_fmaf(1e-5f, Pp, eb - ea);
        const float Dd  = __builtin_fmaf(1e-5f, Pp, 1.f + eb);
        const float invD = rcp_nr(Dd);
        float al = Nn * invD;
        float gg = __builtin_fmaf(onea, invD, 1e-7f);
        if (i == 3 && sub == 15) { al = 0.f; gg = 1.f; }
        w[i] = al; g[i] = gg;
        Gloc *= gg;
    }

    {   // T0: hierarchical product (4x4)
        const float Ga = __shfl(Gloc, g4+0);
        const float Gb = __shfl(Gloc, g4+1);
        const float Gc = __shfl(Gloc, g4+2);
        const float Gd = __shfl(Gloc, g4+3);
        float Tw = 1.0f;
        if (s4 > 0) Tw = Ga;
        if (s4 > 1) Tw *= Gb;
        if (s4 > 2) Tw *= Gc;
        const float Gg = ((Ga*Gb)*Gc)*Gd;
        const float PA = __shfl(Gg, gb+0);
        const float PB = __shfl(Gg, gb+4);
        const float PC = __shfl(Gg, gb+8);
        float Pp = 1.0f;
        if (gq > 0) Pp = PA;
        if (gq > 1) Pp *= PB;
        if (gq > 2) Pp *= PC;
        Gloc = Pp * Tw;                 // T0
    }

    float Tr = Gloc, Sloc = 0.0f;
    #pragma unroll
    for (int i = 0; i < 4; ++i) {
        float ww = __builtin_fmaf(w[i], Tr, 1e-5f);
        if (i == 3 && sub == 15) ww = 0.0f;
        Tr *= g[i];
        Sloc += ww;
        w[i] = ww;
    }

    float Bc, total;
    {   // exclusive prefix (hierarchical canonical)
        const float Sa = __shfl(Sloc, g4+0);
        const float Sb = __shfl(Sloc, g4+1);
        const float Sc = __shfl(Sloc, g4+2);
        const float Sd = __shfl(Sloc, g4+3);
        float W = 0.0f;
        if (s4 > 0) W = Sa;
        if (s4 > 1) W += Sb;
        if (s4 > 2) W += Sc;
        const float Gs = ((Sa+Sb)+Sc)+Sd;
        const float GA = __shfl(Gs, gb+0);
        const float GB = __shfl(Gs, gb+4);
        const float GC = __shfl(Gs, gb+8);
        const float GD = __shfl(Gs, gb+12);
        float Pg = 0.0f;
        if (gq > 0) Pg = GA;
        if (gq > 1) Pg += GB;
        if (gq > 2) Pg += GC;
        Bc    = Pg + W;
        total = ((GA+GB)+GC)+GD;
    }
    const float bandU = 4e-5f * total;
    const float bandW = 4e-3f * total;

    const float U = __builtin_fmaf((float)sub, 0.0625f, 0.03125f) * total;

    int own = 0;
    { const float t = __shfl(Bc, gb + (own|8)); if (t <= U) own |= 8; }
    { const float t = __shfl(Bc, gb + (own|4)); if (t <= U) own |= 4; }
    { const float t = __shfl(Bc, gb + (own|2)); if (t <= U) own |= 2; }
    { const float t = __shfl(Bc, gb + (own|1)); if (t <= U) own |= 1; }
    const int ol = gb + own;

    const float Cown = __shfl(Bc, ol);
    const float w0 = __shfl(w[0], ol);
    const float w1 = __shfl(w[1], ol);
    const float w2 = __shfl(w[2], ol);
    const float w3 = __shfl(w[3], ol);
    const float za = __shfl(z[0], ol);
    const float zb = __shfl(z[1], ol);
    const float zc = __shfl(z[2], ol);
    const float zd = __shfl(z[3], ol);
    const float ze = __shfl(z[4], ol);
    const float wpB = __shfl(w[3], max(ol-1, 0));
    const float wnB = __shfl(w[0], min(ol+1, 63));

    const float c1 = Cown + w0, c2 = c1 + w1, c3 = c2 + w2;
    const int j = (U >= c1) + (U >= c2) + (U >= c3);
    const float cj  = (j==0)?Cown:(j==1)?c1:(j==2)?c2:c3;
    const float wj  = (j==0)?w0:(j==1)?w1:(j==2)?w2:w3;
    const float zj  = (j==0)?za:(j==1)?zb:(j==2)?zc:zd;
    const float zj1 = (j==0)?zb:(j==1)?zc:(j==2)?zd:ze;
    const float wprev = (j==0)?wpB:(j==1)?w0:(j==2)?w1:w2;
    const float wnext = (j==0)?w1:(j==1)?w2:(j==2)?w3:wnB;

    flag |= (wj < bandW);
    flag |= (((U - cj) < bandU) & (wprev < bandW));
    flag |= (((cj + wj - U) < bandU) & (wnext < bandW));

    const float tt = (U - cj) * rcp_nr(wj);
    out[(size_t)ray * NIMP + sub] = __builtin_fmaf(tt, zj1 - zj, zj);

    // ---- group-uniform flag ----
    int fl = flag;
    fl |= __shfl_xor(fl, 1);
    fl |= __shfl_xor(fl, 2);
    fl |= __shfl_xor(fl, 4);
    fl |= __shfl_xor(fl, 8);

    if (!fl) return;

    // ==================== inline f64 redo (rare, group-uniform) ====================
    // Reference numerics (r4-validated): direct 1-alpha+1e-7, division-form
    // cdf comparisons. Inputs reloaded (L2-hot) to keep hot-path VGPRs low.
    const double oxd = (double)ox, oyd = (double)oy, ozd = (double)oz;
    const double dxd = (double)dx, dyd = (double)dy, dzd = (double)dz;

    double zD[5], sD[5];
    {
        const float4 a = *reinterpret_cast<const float4*>(zp);
        const float4 b = *reinterpret_cast<const float4*>(sp);
        zD[0]=a.x; zD[1]=a.y; zD[2]=a.z; zD[3]=a.w;
        sD[0]=b.x; sD[1]=b.y; sD[2]=b.z; sD[3]=b.w;
    }
    zD[4] = __shfl_down(zD[0], 1);   // sub15: garbage, provably unused
    sD[4] = __shfl_down(sD[0], 1);

    double ivD[4];
    ivD[0] = (double)ip[0]; ivD[1] = (double)ip[1]; ivD[2] = (double)ip[2];
    ivD[3] = (sub < 15) ? (double)ip[3] : 0.0;

    unsigned md = 0;
    #pragma unroll
    for (int i = 0; i < 4; ++i) {
        const double px = oxd + dxd*zD[i];
        const double py = oyd + dyd*zD[i];
        const double pz = ozd + dzd*zD[i];
        if (fabs(px) <= SIDE && fabs(py) <= SIDE && fabs(pz) <= SIDE)
            md |= (1u << i);
    }
    md |= (__shfl_down(md, 1) & 1u) << 4;   // sub15 bit: garbage, overridden

    const double cvl = (sD[4]-sD[3]) / (zD[4]-zD[3] + 1e-5);
    double pvc = __shfl_up(cvl, 1);
    if (sub == 0) pvc = 0.0;

    double wD[4], gD[4];
    double Gl = 1.0;
    #pragma unroll
    for (int i = 0; i < 4; ++i) {
        const double cv0 = (sD[i+1]-sD[i]) / (zD[i+1]-zD[i] + 1e-5);
        double cv = fmin(pvc, cv0);
        pvc = cv0;
        const double inside = ((md >> i) & 3u) ? 1.0 : 0.0;
        cv = fmin(fmax(cv, -1000.0), 0.0) * inside;
        const double mid  = 0.5 * (sD[i] + sD[i+1]);
        const double dist = zD[i+1] - zD[i];
        const double arg_p = (mid - cv * dist * 0.5) * ivD[i];
        const double arg_n = (mid + cv * dist * 0.5) * ivD[i];
        const double a = exp_fast(fmin(fmax(-arg_p, -350.0), 350.0));
        const double b = exp_fast(fmin(fmax(-arg_n, -350.0), 350.0));
        const double P = (1.0 + a) * (1.0 + b);
        double alpha = (__builtin_fma(1e-5, P, b - a)) /
                       (__builtin_fma(1e-5, P, 1.0 + b));
        double gg = 1.0 - alpha + 1e-7;
        if (i == 3 && sub == 15) { alpha = 0.0; gg = 1.0; }
        wD[i] = alpha; gD[i] = gg;
        Gl *= gg;
    }

    {   // T0 hierarchical (f64)
        const double Ga = __shfl(Gl, g4+0);
        const double Gb = __shfl(Gl, g4+1);
        const double Gc = __shfl(Gl, g4+2);
        const double Gd = __shfl(Gl, g4+3);
        double Tw = 1.0;
        if (s4 > 0) Tw = Ga;
        if (s4 > 1) Tw *= Gb;
        if (s4 > 2) Tw *= Gc;
        const double Gg = ((Ga*Gb)*Gc)*Gd;
        const double PA = __shfl(Gg, gb+0);
        const double PB = __shfl(Gg, gb+4);
        const double PC = __shfl(Gg, gb+8);
        double Pp = 1.0;
        if (gq > 0) Pp = PA;
        if (gq > 1) Pp *= PB;
        if (gq > 2) Pp *= PC;
        Gl = Pp * Tw;                    // T0
    }

    double TrD = Gl, Sl = 0.0;
    #pragma unroll
    for (int i = 0; i < 4; ++i) {
        double ww = wD[i] * TrD + 1e-5;
        if (i == 3 && sub == 15) ww = 0.0;
        TrD *= gD[i];
        Sl += ww;
        wD[i] = ww;
    }

    double BcD, totD;
    {
        const double Sa = __shfl(Sl, g4+0);
        const double Sb = __shfl(Sl, g4+1);
        const double Sc = __shfl(Sl, g4+2);
        const double Sd = __shfl(Sl, g4+3);
        double W = 0.0;
        if (s4 > 0) W = Sa;
        if (s4 > 1) W += Sb;
        if (s4 > 2) W += Sc;
        const double Gs = ((Sa+Sb)+Sc)+Sd;
        const double GA = __shfl(Gs, gb+0);
        const double GB = __shfl(Gs, gb+4);
        const double GC = __shfl(Gs, gb+8);
        const double GD = __shfl(Gs, gb+12);
        double Pg = 0.0;
        if (gq > 0) Pg = GA;
        if (gq > 1) Pg += GB;
        if (gq > 2) Pg += GC;
        BcD  = Pg + W;
        totD = ((GA+GB)+GC)+GD;
    }

    const double ud = 0.03125 + 0.0625 * (double)sub;   // exact

    int ow = 0;   // largest q with cdf(Bc_q) <= u   (division form, as r4)
    { const double t = __shfl(BcD, gb + (ow|8)); if (t/totD <= ud) ow |= 8; }
    { const double t = __shfl(BcD, gb + (ow|4)); if (t/totD <= ud) ow |= 4; }
    { const double t = __shfl(BcD, gb + (ow|2)); if (t/totD <= ud) ow |= 2; }
    { const double t = __shfl(BcD, gb + (ow|1)); if (t/totD <= ud) ow |= 1; }
    const int ol2 = gb + ow;

    const double CoD = __shfl(BcD, ol2);
    const double u0D = __shfl(wD[0], ol2);
    const double u1D = __shfl(wD[1], ol2);
    const double u2D = __shfl(wD[2], ol2);
    const double u3D = __shfl(wD[3], ol2);
    const double zaD = __shfl(zD[0], ol2);
    const double zbD = __shfl(zD[1], ol2);
    const double zcD = __shfl(zD[2], ol2);
    const double zdD = __shfl(zD[3], ol2);
    const double zeD = __shfl(zD[4], ol2);

    const double d1 = CoD + u0D, d2 = d1 + u1D, d3 = d2 + u2D;
    const int jj = (d1/totD <= ud) + (d2/totD <= ud) + (d3/totD <= ud);
    const double cjD  = (jj==0)?CoD:(jj==1)?d1:(jj==2)?d2:d3;
    const double wjD  = (jj==0)?u0D:(jj==1)?u1D:(jj==2)?u2D:u3D;
    const double zjD  = (jj==0)?zaD:(jj==1)?zbD:(jj==2)?zcD:zdD;
    const double zj1D = (jj==0)?zbD:(jj==1)?zcD:(jj==2)?zdD:zeD;

    const double cdfb = cjD / totD;
    const double cdfa = (cjD + wjD) / totD;
    double den = cdfa - cdfb;
    den = (den < 1e-5) ? 1.0 : den;
    const double tD = (ud - cdfb) / den;
    const double rD = zjD + tD * (zj1D - zjD);

    out[(size_t)ray * NIMP + sub] = (float)rD;
}

// ============================================================================
// Fallback (n != 16): validated r4/r7 f64 wave-per-ray over ALL rays.
// ============================================================================
__global__ __launch_bounds__(256) void neus_redo_kernel(
    const float* __restrict__ rays_o,
    const float* __restrict__ rays_d,
    const float* __restrict__ z_vals,
    const float* __restrict__ sdf,
    const float* __restrict__ inv_s,
    float* __restrict__ out,
    int B, int n_imp, double u0, double du)
{
    const int lane = threadIdx.x & 63;
    const int wv   = blockIdx.x * 4 + (threadIdx.x >> 6);

    for (unsigned i = wv; i < (unsigned)B; i += 1024) {
        const int ray = (int)i;

        const double z = (double)z_vals[(size_t)ray * 64 + lane];
        const double s = (double)sdf   [(size_t)ray * 64 + lane];
        double isv = 0.0;
        if (lane < 63) isv = (double)inv_s[(size_t)ray * 63 + lane];

        const double ox = (double)rays_o[(size_t)ray*3+0];
        const double oy = (double)rays_o[(size_t)ray*3+1];
        const double oz = (double)rays_o[(size_t)ray*3+2];
        const double dx = (double)rays_d[(size_t)ray*3+0];
        const double dy = (double)rays_d[(size_t)ray*3+1];
        const double dz = (double)rays_d[(size_t)ray*3+2];

        const double px = ox + dx*z, py = oy + dy*z, pz = oz + dz*z;
        const double inner = (fabs(px) <= SIDE && fabs(py) <= SIDE && fabs(pz) <= SIDE) ? 1.0 : 0.0;

        const double next_s  = __shfl_down(s, 1);
        const double next_z  = __shfl_down(z, 1);
        const double inner_n = __shfl_down(inner, 1);

        const double inside = ((inner > 0.5) || (inner_n > 0.5)) ? 1.0 : 0.0;
        const double mid    = 0.5 * (s + next_s);
        const double cv0    = (next_s - s) / (next_z - z + 1e-5);
        double prevc = __shfl_up(cv0, 1);
        if (lane == 0) prevc = 0.0;
        double cv = fmin(prevc, cv0);
        cv = fmin(fmax(cv, -1000.0), 0.0) * inside;
        const double dist = next_z - z;

        const double arg_p = (mid - cv * dist * 0.5) * isv;
        const double arg_n = (mid + cv * dist * 0.5) * isv;
        const double a = exp_fast(fmin(fmax(-arg_p, -350.0), 350.0));
        const double b = exp_fast(fmin(fmax(-arg_n, -350.0), 350.0));
        const double P = (1.0 + a) * (1.0 + b);
        const double alpha = (__builtin_fma(1e-5, P, b - a)) /
                             (__builtin_fma(1e-5, P, 1.0 + b));

        double g = (lane < 63) ? (1.0 - alpha + 1e-7) : 1.0;
        double p = g;
        #pragma unroll
        for (int off = 1; off < 64; off <<= 1) {
            double tmp = __shfl_up(p, off);
            if (lane >= off) p *= tmp;
        }
        double trans = __shfl_up(p, 1);
        if (lane == 0) trans = 1.0;

        const double w = (lane < 63) ? (alpha * trans + 1e-5) : 0.0;

        double sc = w;
        #pragma unroll
        for (int off = 1; off < 64; off <<= 1) {
            double tmp = __shfl_up(sc, off);
            if (lane >= off) sc += tmp;
        }
        const double total = __shfl(sc, 63);
        const double excl  = sc - w;
        const double cdf   = excl / total;

        const double u = u0 + du * (double)lane;
        int lo = 0, hi = 64;
        #pragma unroll
        for (int it = 0; it < 7; ++it) {
            const int m  = (lo + hi) >> 1;
            const double cm = __shfl(cdf, m);
            if (lo < hi) {
                if (cm <= u) lo = m + 1; else hi = m;
            }
        }
        const int ind   = lo;
        const int below = max(ind - 1, 0);
        const int above = min(ind, 63);

        const double cb = __shfl(cdf, below);
        const double ca = __shfl(cdf, above);
        const double bb = __shfl(z, below);
        const double ba = __shfl(z, above);

        double denom = ca - cb;
        denom = (denom < 1e-5) ? 1.0 : denom;
        const double tt  = (u - cb) / denom;
        const double r2  = bb + tt * (ba - bb);

        if (lane < n_imp) out[(size_t)ray * n_imp + lane] = (float)r2;
    }
}

extern "C" void kernel_launch(void* const* d_in, const int* in_sizes, int n_in,
                              void* d_out, int out_size, void* d_ws, size_t ws_size,
                              hipStream_t stream) {
    const float* rays_o = (const float*)d_in[0];
    const float* rays_d = (const float*)d_in[1];
    const float* z_vals = (const float*)d_in[2];
    const float* sdf    = (const float*)d_in[3];
    const float* inv_s  = (const float*)d_in[4];
    float* out = (float*)d_out;

    const int B = in_sizes[0] / 3;          // 131072
    const int n = out_size / B;             // n_importance = 16

    if (n == NIMP) {
        const long long threads = (long long)B * 16;
        neus_fused_kernel<<<(int)((threads + 255) / 256), 256, 0, stream>>>(
            rays_o, rays_d, z_vals, sdf, inv_s, out, B);
    } else {
        const double u0 = 0.5 / (double)n;
        const double du = (n > 1) ? ((1.0 - 1.0 / (double)n) / (double)(n - 1)) : 0.0;
        neus_redo_kernel<<<256, 256, 0, stream>>>(
            rays_o, rays_d, z_vals, sdf, inv_s, out, B, n, u0, du);
    }
}

// Round 15
// 31.073 us; speedup vs baseline: 2.4821x; 1.1571x over previous
//
#include <hip/hip_runtime.h>
#include <math.h>

#define SIDE 0.6
#define NIMP 16

// ---------- fast f64 exp, |x| <= 350, rel err ~1e-15 (validated r3/r4) ----------
__device__ __forceinline__ double exp_fast(double x) {
    const double INVLN2 = 1.44269504088896338700e+00;
    const double LN2HI  = 6.93147180369123816490e-01;
    const double LN2LO  = 1.90821492927058770002e-10;
    const double kd = __builtin_rint(x * INVLN2);
    const int    k  = (int)kd;
    double r = __builtin_fma(-kd, LN2HI, x);
    r        = __builtin_fma(-kd, LN2LO, r);
    double p =               2.08767569878681e-09;
    p = __builtin_fma(p, r,  2.50521083854417e-08);
    p = __builtin_fma(p, r,  2.75573192239859e-07);
    p = __builtin_fma(p, r,  2.75573192239859e-06);
    p = __builtin_fma(p, r,  2.48015873015873e-05);
    p = __builtin_fma(p, r,  1.98412698412698e-04);
    p = __builtin_fma(p, r,  1.38888888888889e-03);
    p = __builtin_fma(p, r,  8.33333333333333e-03);
    p = __builtin_fma(p, r,  4.16666666666667e-02);
    p = __builtin_fma(p, r,  1.66666666666667e-01);
    p = __builtin_fma(p, r,  5.00000000000000e-01);
    p = __builtin_fma(p, r,  1.0);
    p = __builtin_fma(p, r,  1.0);
    const long long bits = (long long)(1023 + k) << 52;
    return p * __longlong_as_double(bits);
}

#if __has_builtin(__builtin_amdgcn_rcpf)
__device__ __forceinline__ float rcp_nr(float x) {   // ~0.5 ulp: v_rcp + 1 NR
    float r = __builtin_amdgcn_rcpf(x);
    return __builtin_fmaf(__builtin_fmaf(-x, r, 1.0f), r, r);
}
#else
__device__ __forceinline__ float rcp_nr(float x) { return 1.0f / x; }
#endif

// hardware exp: v_mul + v_exp_f32 (rel err ~2.4e-6 incl. arg scaling) —
// replaces the 11-op poly (r14 postmortem: alpha-loop exps were ~40% of the
// hot path). All discrete decisions remain protected by the flag bands
// (bandU 4e-5 >= 10x the accumulated cdf error).
__device__ __forceinline__ float exp_hw(float x) { return __expf(x); }

// ============================================================================
// FUSED kernel (r14 structure): f32 fast path (16 lanes/ray, 4 intervals/lane,
// lane-per-sample emission) + inline group-uniform f64 redo for flagged rays.
// r15 changes: hardware v_exp_f32 (hot path -35%), bandW 4e-3 -> 1e-3
// (cold-path tail ~4x smaller; flip-error bound 9.2e-3 << 4.4e-2 threshold).
// ============================================================================
__global__ __launch_bounds__(256) void neus_fused_kernel(
    const float* __restrict__ rays_o,
    const float* __restrict__ rays_d,
    const float* __restrict__ z_vals,
    const float* __restrict__ sdf,
    const float* __restrict__ inv_s,
    float* __restrict__ out,
    int B)
{
    const int tid  = blockIdx.x * 256 + threadIdx.x;
    const int ray  = tid >> 4;          // 16 lanes per ray
    const int sub  = tid & 15;
    if (ray >= B) return;

    const int lane = threadIdx.x & 63;
    const int gb   = lane & ~15;        // ray-group base lane
    const int g4   = lane & ~3;         // 4-lane subgroup base
    const int s4   = sub & 3;
    const int gq   = sub >> 2;

    const float* zp = z_vals + (size_t)ray * 64 + sub * 4;
    const float* sp = sdf    + (size_t)ray * 64 + sub * 4;
    const float* ip = inv_s  + (size_t)ray * 63 + sub * 4;

    const float ox = rays_o[(size_t)ray*3+0];
    const float oy = rays_o[(size_t)ray*3+1];
    const float oz = rays_o[(size_t)ray*3+2];
    const float dx = rays_d[(size_t)ray*3+0];
    const float dy = rays_d[(size_t)ray*3+1];
    const float dz = rays_d[(size_t)ray*3+2];

    // ==================== f32 fast path ====================
    float z[5], s[5];
    {
        const float4 a = *reinterpret_cast<const float4*>(zp);
        const float4 b = *reinterpret_cast<const float4*>(sp);
        z[0]=a.x; z[1]=a.y; z[2]=a.z; z[3]=a.w;
        s[0]=b.x; s[1]=b.y; s[2]=b.z; s[3]=b.w;
    }
    z[4] = __shfl_down(z[0], 1);
    s[4] = __shfl_down(s[0], 1);

    float iv[4];
    iv[0] = ip[0]; iv[1] = ip[1]; iv[2] = ip[2];
    iv[3] = (sub < 15) ? ip[3] : 0.0f;

    int flag = 0;
    unsigned m = 0;
    #pragma unroll
    for (int i = 0; i < 4; ++i) {
        const float px = __builtin_fmaf(dx, z[i], ox);
        const float py = __builtin_fmaf(dy, z[i], oy);
        const float pz = __builtin_fmaf(dz, z[i], oz);
        const float ax = fabsf(px), ay = fabsf(py), az = fabsf(pz);
        if (ax <= 0.6f && ay <= 0.6f && az <= 0.6f) m |= (1u << i);
        const float d3 = fminf(fminf(fabsf(ax-0.6f), fabsf(ay-0.6f)),
                               fabsf(az-0.6f));
        flag |= (d3 < 1e-5f);
    }
    m |= (__shfl_down(m, 1) & 1u) << 4;

    const float cv0_last = (s[4]-s[3]) * rcp_nr(z[4]-z[3] + 1e-5f);
    float prevc = __shfl_up(cv0_last, 1);
    if (sub == 0) prevc = 0.0f;

    float w[4], g[4];
    float Gloc = 1.0f;
    #pragma unroll
    for (int i = 0; i < 4; ++i) {
        const float cv0 = (s[i+1]-s[i]) * rcp_nr(z[i+1]-z[i] + 1e-5f);
        float cv = fminf(prevc, cv0);
        prevc = cv0;
        const float inside = ((m >> i) & 3u) ? 1.0f : 0.0f;
        cv = fminf(fmaxf(cv, -1000.f), 0.f) * inside;
        const float mid = 0.5f * (s[i] + s[i+1]);
        const float dzz = z[i+1] - z[i];
        const float q2  = cv * (dzz * 0.5f);
        const float apv = (mid - q2) * iv[i];
        const float anv = (mid + q2) * iv[i];
        const float ea = exp_hw(fminf(fmaxf(-apv, -40.f), 40.f));
        const float eb = exp_hw(fminf(fmaxf(-anv, -40.f), 40.f));
        const float onea = 1.f + ea;
        const float Pp  = onea * (1.f + eb);
        const float Nn  = __builtin_fmaf(1e-5f, Pp, eb - ea);
        const float Dd  = __builtin_fmaf(1e-5f, Pp, 1.f + eb);
        const float invD = rcp_nr(Dd);
        float al = Nn * invD;
        float gg = __builtin_fmaf(onea, invD, 1e-7f);
        if (i == 3 && sub == 15) { al = 0.f; gg = 1.f; }
        w[i] = al; g[i] = gg;
        Gloc *= gg;
    }

    {   // T0: hierarchical product (4x4)
        const float Ga = __shfl(Gloc, g4+0);
        const float Gb = __shfl(Gloc, g4+1);
        const float Gc = __shfl(Gloc, g4+2);
        const float Gd = __shfl(Gloc, g4+3);
        float Tw = 1.0f;
        if (s4 > 0) Tw = Ga;
        if (s4 > 1) Tw *= Gb;
        if (s4 > 2) Tw *= Gc;
        const float Gg = ((Ga*Gb)*Gc)*Gd;
        const float PA = __shfl(Gg, gb+0);
        const float PB = __shfl(Gg, gb+4);
        const float PC = __shfl(Gg, gb+8);
        float Pp = 1.0f;
        if (gq > 0) Pp = PA;
        if (gq > 1) Pp *= PB;
        if (gq > 2) Pp *= PC;
        Gloc = Pp * Tw;                 // T0
    }

    float Tr = Gloc, Sloc = 0.0f;
    #pragma unroll
    for (int i = 0; i < 4; ++i) {
        float ww = __builtin_fmaf(w[i], Tr, 1e-5f);
        if (i == 3 && sub == 15) ww = 0.0f;
        Tr *= g[i];
        Sloc += ww;
        w[i] = ww;
    }

    float Bc, total;
    {   // exclusive prefix (hierarchical canonical)
        const float Sa = __shfl(Sloc, g4+0);
        const float Sb = __shfl(Sloc, g4+1);
        const float Sc = __shfl(Sloc, g4+2);
        const float Sd = __shfl(Sloc, g4+3);
        float W = 0.0f;
        if (s4 > 0) W = Sa;
        if (s4 > 1) W += Sb;
        if (s4 > 2) W += Sc;
        const float Gs = ((Sa+Sb)+Sc)+Sd;
        const float GA = __shfl(Gs, gb+0);
        const float GB = __shfl(Gs, gb+4);
        const float GC = __shfl(Gs, gb+8);
        const float GD = __shfl(Gs, gb+12);
        float Pg = 0.0f;
        if (gq > 0) Pg = GA;
        if (gq > 1) Pg += GB;
        if (gq > 2) Pg += GC;
        Bc    = Pg + W;
        total = ((GA+GB)+GC)+GD;
    }
    const float bandU = 4e-5f * total;
    const float bandW = 1e-3f * total;   // r15: narrowed 4e-3 -> 1e-3

    const float U = __builtin_fmaf((float)sub, 0.0625f, 0.03125f) * total;

    int own = 0;
    { const float t = __shfl(Bc, gb + (own|8)); if (t <= U) own |= 8; }
    { const float t = __shfl(Bc, gb + (own|4)); if (t <= U) own |= 4; }
    { const float t = __shfl(Bc, gb + (own|2)); if (t <= U) own |= 2; }
    { const float t = __shfl(Bc, gb + (own|1)); if (t <= U) own |= 1; }
    const int ol = gb + own;

    const float Cown = __shfl(Bc, ol);
    const float w0 = __shfl(w[0], ol);
    const float w1 = __shfl(w[1], ol);
    const float w2 = __shfl(w[2], ol);
    const float w3 = __shfl(w[3], ol);
    const float za = __shfl(z[0], ol);
    const float zb = __shfl(z[1], ol);
    const float zc = __shfl(z[2], ol);
    const float zd = __shfl(z[3], ol);
    const float ze = __shfl(z[4], ol);
    const float wpB = __shfl(w[3], max(ol-1, 0));
    const float wnB = __shfl(w[0], min(ol+1, 63));

    const float c1 = Cown + w0, c2 = c1 + w1, c3 = c2 + w2;
    const int j = (U >= c1) + (U >= c2) + (U >= c3);
    const float cj  = (j==0)?Cown:(j==1)?c1:(j==2)?c2:c3;
    const float wj  = (j==0)?w0:(j==1)?w1:(j==2)?w2:w3;
    const float zj  = (j==0)?za:(j==1)?zb:(j==2)?zc:zd;
    const float zj1 = (j==0)?zb:(j==1)?zc:(j==2)?zd:ze;
    const float wprev = (j==0)?wpB:(j==1)?w0:(j==2)?w1:w2;
    const float wnext = (j==0)?w1:(j==1)?w2:(j==2)?w3:wnB;

    flag |= (wj < bandW);
    flag |= (((U - cj) < bandU) & (wprev < bandW));
    flag |= (((cj + wj - U) < bandU) & (wnext < bandW));

    const float tt = (U - cj) * rcp_nr(wj);
    out[(size_t)ray * NIMP + sub] = __builtin_fmaf(tt, zj1 - zj, zj);

    // ---- group-uniform flag ----
    int fl = flag;
    fl |= __shfl_xor(fl, 1);
    fl |= __shfl_xor(fl, 2);
    fl |= __shfl_xor(fl, 4);
    fl |= __shfl_xor(fl, 8);

    if (!fl) return;

    // ==================== inline f64 redo (rare, group-uniform) ====================
    const double oxd = (double)ox, oyd = (double)oy, ozd = (double)oz;
    const double dxd = (double)dx, dyd = (double)dy, dzd = (double)dz;

    double zD[5], sD[5];
    {
        const float4 a = *reinterpret_cast<const float4*>(zp);
        const float4 b = *reinterpret_cast<const float4*>(sp);
        zD[0]=a.x; zD[1]=a.y; zD[2]=a.z; zD[3]=a.w;
        sD[0]=b.x; sD[1]=b.y; sD[2]=b.z; sD[3]=b.w;
    }
    zD[4] = __shfl_down(zD[0], 1);   // sub15: garbage, provably unused
    sD[4] = __shfl_down(sD[0], 1);

    double ivD[4];
    ivD[0] = (double)ip[0]; ivD[1] = (double)ip[1]; ivD[2] = (double)ip[2];
    ivD[3] = (sub < 15) ? (double)ip[3] : 0.0;

    unsigned md = 0;
    #pragma unroll
    for (int i = 0; i < 4; ++i) {
        const double px = oxd + dxd*zD[i];
        const double py = oyd + dyd*zD[i];
        const double pz = ozd + dzd*zD[i];
        if (fabs(px) <= SIDE && fabs(py) <= SIDE && fabs(pz) <= SIDE)
            md |= (1u << i);
    }
    md |= (__shfl_down(md, 1) & 1u) << 4;

    const double cvl = (sD[4]-sD[3]) / (zD[4]-zD[3] + 1e-5);
    double pvc = __shfl_up(cvl, 1);
    if (sub == 0) pvc = 0.0;

    double wD[4], gD[4];
    double Gl = 1.0;
    #pragma unroll
    for (int i = 0; i < 4; ++i) {
        const double cv0 = (sD[i+1]-sD[i]) / (zD[i+1]-zD[i] + 1e-5);
        double cv = fmin(pvc, cv0);
        pvc = cv0;
        const double inside = ((md >> i) & 3u) ? 1.0 : 0.0;
        cv = fmin(fmax(cv, -1000.0), 0.0) * inside;
        const double mid  = 0.5 * (sD[i] + sD[i+1]);
        const double dist = zD[i+1] - zD[i];
        const double arg_p = (mid - cv * dist * 0.5) * ivD[i];
        const double arg_n = (mid + cv * dist * 0.5) * ivD[i];
        const double a = exp_fast(fmin(fmax(-arg_p, -350.0), 350.0));
        const double b = exp_fast(fmin(fmax(-arg_n, -350.0), 350.0));
        const double P = (1.0 + a) * (1.0 + b);
        double alpha = (__builtin_fma(1e-5, P, b - a)) /
                       (__builtin_fma(1e-5, P, 1.0 + b));
        double gg = 1.0 - alpha + 1e-7;
        if (i == 3 && sub == 15) { alpha = 0.0; gg = 1.0; }
        wD[i] = alpha; gD[i] = gg;
        Gl *= gg;
    }

    {   // T0 hierarchical (f64)
        const double Ga = __shfl(Gl, g4+0);
        const double Gb = __shfl(Gl, g4+1);
        const double Gc = __shfl(Gl, g4+2);
        const double Gd = __shfl(Gl, g4+3);
        double Tw = 1.0;
        if (s4 > 0) Tw = Ga;
        if (s4 > 1) Tw *= Gb;
        if (s4 > 2) Tw *= Gc;
        const double Gg = ((Ga*Gb)*Gc)*Gd;
        const double PA = __shfl(Gg, gb+0);
        const double PB = __shfl(Gg, gb+4);
        const double PC = __shfl(Gg, gb+8);
        double Pp = 1.0;
        if (gq > 0) Pp = PA;
        if (gq > 1) Pp *= PB;
        if (gq > 2) Pp *= PC;
        Gl = Pp * Tw;                    // T0
    }

    double TrD = Gl, Sl = 0.0;
    #pragma unroll
    for (int i = 0; i < 4; ++i) {
        double ww = wD[i] * TrD + 1e-5;
        if (i == 3 && sub == 15) ww = 0.0;
        TrD *= gD[i];
        Sl += ww;
        wD[i] = ww;
    }

    double BcD, totD;
    {
        const double Sa = __shfl(Sl, g4+0);
        const double Sb = __shfl(Sl, g4+1);
        const double Sc = __shfl(Sl, g4+2);
        const double Sd = __shfl(Sl, g4+3);
        double W = 0.0;
        if (s4 > 0) W = Sa;
        if (s4 > 1) W += Sb;
        if (s4 > 2) W += Sc;
        const double Gs = ((Sa+Sb)+Sc)+Sd;
        const double GA = __shfl(Gs, gb+0);
        const double GB = __shfl(Gs, gb+4);
        const double GC = __shfl(Gs, gb+8);
        const double GD = __shfl(Gs, gb+12);
        double Pg = 0.0;
        if (gq > 0) Pg = GA;
        if (gq > 1) Pg += GB;
        if (gq > 2) Pg += GC;
        BcD  = Pg + W;
        totD = ((GA+GB)+GC)+GD;
    }

    const double ud = 0.03125 + 0.0625 * (double)sub;   // exact

    int ow = 0;   // largest q with cdf(Bc_q) <= u (division form, as r4)
    { const double t = __shfl(BcD, gb + (ow|8)); if (t/totD <= ud) ow |= 8; }
    { const double t = __shfl(BcD, gb + (ow|4)); if (t/totD <= ud) ow |= 4; }
    { const double t = __shfl(BcD, gb + (ow|2)); if (t/totD <= ud) ow |= 2; }
    { const double t = __shfl(BcD, gb + (ow|1)); if (t/totD <= ud) ow |= 1; }
    const int ol2 = gb + ow;

    const double CoD = __shfl(BcD, ol2);
    const double u0D = __shfl(wD[0], ol2);
    const double u1D = __shfl(wD[1], ol2);
    const double u2D = __shfl(wD[2], ol2);
    const double u3D = __shfl(wD[3], ol2);
    const double zaD = __shfl(zD[0], ol2);
    const double zbD = __shfl(zD[1], ol2);
    const double zcD = __shfl(zD[2], ol2);
    const double zdD = __shfl(zD[3], ol2);
    const double zeD = __shfl(zD[4], ol2);

    const double d1 = CoD + u0D, d2 = d1 + u1D, d3 = d2 + u2D;
    const int jj = (d1/totD <= ud) + (d2/totD <= ud) + (d3/totD <= ud);
    const double cjD  = (jj==0)?CoD:(jj==1)?d1:(jj==2)?d2:d3;
    const double wjD  = (jj==0)?u0D:(jj==1)?u1D:(jj==2)?u2D:u3D;
    const double zjD  = (jj==0)?zaD:(jj==1)?zbD:(jj==2)?zcD:zdD;
    const double zj1D = (jj==0)?zbD:(jj==1)?zcD:(jj==2)?zdD:zeD;

    const double cdfb = cjD / totD;
    const double cdfa = (cjD + wjD) / totD;
    double den = cdfa - cdfb;
    den = (den < 1e-5) ? 1.0 : den;
    const double tD = (ud - cdfb) / den;
    const double rD = zjD + tD * (zj1D - zjD);

    out[(size_t)ray * NIMP + sub] = (float)rD;
}

// ============================================================================
// Fallback (n != 16): validated r4/r7 f64 wave-per-ray over ALL rays.
// ============================================================================
__global__ __launch_bounds__(256) void neus_redo_kernel(
    const float* __restrict__ rays_o,
    const float* __restrict__ rays_d,
    const float* __restrict__ z_vals,
    const float* __restrict__ sdf,
    const float* __restrict__ inv_s,
    float* __restrict__ out,
    int B, int n_imp, double u0, double du)
{
    const int lane = threadIdx.x & 63;
    const int wv   = blockIdx.x * 4 + (threadIdx.x >> 6);

    for (unsigned i = wv; i < (unsigned)B; i += 1024) {
        const int ray = (int)i;

        const double z = (double)z_vals[(size_t)ray * 64 + lane];
        const double s = (double)sdf   [(size_t)ray * 64 + lane];
        double isv = 0.0;
        if (lane < 63) isv = (double)inv_s[(size_t)ray * 63 + lane];

        const double ox = (double)rays_o[(size_t)ray*3+0];
        const double oy = (double)rays_o[(size_t)ray*3+1];
        const double oz = (double)rays_o[(size_t)ray*3+2];
        const double dx = (double)rays_d[(size_t)ray*3+0];
        const double dy = (double)rays_d[(size_t)ray*3+1];
        const double dz = (double)rays_d[(size_t)ray*3+2];

        const double px = ox + dx*z, py = oy + dy*z, pz = oz + dz*z;
        const double inner = (fabs(px) <= SIDE && fabs(py) <= SIDE && fabs(pz) <= SIDE) ? 1.0 : 0.0;

        const double next_s  = __shfl_down(s, 1);
        const double next_z  = __shfl_down(z, 1);
        const double inner_n = __shfl_down(inner, 1);

        const double inside = ((inner > 0.5) || (inner_n > 0.5)) ? 1.0 : 0.0;
        const double mid    = 0.5 * (s + next_s);
        const double cv0    = (next_s - s) / (next_z - z + 1e-5);
        double prevc = __shfl_up(cv0, 1);
        if (lane == 0) prevc = 0.0;
        double cv = fmin(prevc, cv0);
        cv = fmin(fmax(cv, -1000.0), 0.0) * inside;
        const double dist = next_z - z;

        const double arg_p = (mid - cv * dist * 0.5) * isv;
        const double arg_n = (mid + cv * dist * 0.5) * isv;
        const double a = exp_fast(fmin(fmax(-arg_p, -350.0), 350.0));
        const double b = exp_fast(fmin(fmax(-arg_n, -350.0), 350.0));
        const double P = (1.0 + a) * (1.0 + b);
        const double alpha = (__builtin_fma(1e-5, P, b - a)) /
                             (__builtin_fma(1e-5, P, 1.0 + b));

        double g = (lane < 63) ? (1.0 - alpha + 1e-7) : 1.0;
        double p = g;
        #pragma unroll
        for (int off = 1; off < 64; off <<= 1) {
            double tmp = __shfl_up(p, off);
            if (lane >= off) p *= tmp;
        }
        double trans = __shfl_up(p, 1);
        if (lane == 0) trans = 1.0;

        const double w = (lane < 63) ? (alpha * trans + 1e-5) : 0.0;

        double sc = w;
        #pragma unroll
        for (int off = 1; off < 64; off <<= 1) {
            double tmp = __shfl_up(sc, off);
            if (lane >= off) sc += tmp;
        }
        const double total = __shfl(sc, 63);
        const double excl  = sc - w;
        const double cdf   = excl / total;

        const double u = u0 + du * (double)lane;
        int lo = 0, hi = 64;
        #pragma unroll
        for (int it = 0; it < 7; ++it) {
            const int m  = (lo + hi) >> 1;
            const double cm = __shfl(cdf, m);
            if (lo < hi) {
                if (cm <= u) lo = m + 1; else hi = m;
            }
        }
        const int ind   = lo;
        const int below = max(ind - 1, 0);
        const int above = min(ind, 63);

        const double cb = __shfl(cdf, below);
        const double ca = __shfl(cdf, above);
        const double bb = __shfl(z, below);
        const double ba = __shfl(z, above);

        double denom = ca - cb;
        denom = (denom < 1e-5) ? 1.0 : denom;
        const double tt  = (u - cb) / denom;
        const double r2  = bb + tt * (ba - bb);

        if (lane < n_imp) out[(size_t)ray * n_imp + lane] = (float)r2;
    }
}

extern "C" void kernel_launch(void* const* d_in, const int* in_sizes, int n_in,
                              void* d_out, int out_size, void* d_ws, size_t ws_size,
                              hipStream_t stream) {
    const float* rays_o = (const float*)d_in[0];
    const float* rays_d = (const float*)d_in[1];
    const float* z_vals = (const float*)d_in[2];
    const float* sdf    = (const float*)d_in[3];
    const float* inv_s  = (const float*)d_in[4];
    float* out = (float*)d_out;

    const int B = in_sizes[0] / 3;          // 131072
    const int n = out_size / B;             // n_importance = 16

    if (n == NIMP) {
        const long long threads = (long long)B * 16;
        neus_fused_kernel<<<(int)((threads + 255) / 256), 256, 0, stream>>>(
            rays_o, rays_d, z_vals, sdf, inv_s, out, B);
    } else {
        const double u0 = 0.5 / (double)n;
        const double du = (n > 1) ? ((1.0 - 1.0 / (double)n) / (double)(n - 1)) : 0.0;
        neus_redo_kernel<<<256, 256, 0, stream>>>(
            rays_o, rays_d, z_vals, sdf, inv_s, out, B, n, u0, du);
    }
}

// Round 16
// 29.261 us; speedup vs baseline: 2.6358x; 1.0619x over previous
//
#include <hip/hip_runtime.h>
#include <math.h>

#define SIDE 0.6
#define NIMP 16

// ---------- fast f64 exp, |x| <= 350, rel err ~1e-15 (validated r3/r4) ----------
__device__ __forceinline__ double exp_fast(double x) {
    const double INVLN2 = 1.44269504088896338700e+00;
    const double LN2HI  = 6.93147180369123816490e-01;
    const double LN2LO  = 1.90821492927058770002e-10;
    const double kd = __builtin_rint(x * INVLN2);
    const int    k  = (int)kd;
    double r = __builtin_fma(-kd, LN2HI, x);
    r        = __builtin_fma(-kd, LN2LO, r);
    double p =               2.08767569878681e-09;
    p = __builtin_fma(p, r,  2.50521083854417e-08);
    p = __builtin_fma(p, r,  2.75573192239859e-07);
    p = __builtin_fma(p, r,  2.75573192239859e-06);
    p = __builtin_fma(p, r,  2.48015873015873e-05);
    p = __builtin_fma(p, r,  1.98412698412698e-04);
    p = __builtin_fma(p, r,  1.38888888888889e-03);
    p = __builtin_fma(p, r,  8.33333333333333e-03);
    p = __builtin_fma(p, r,  4.16666666666667e-02);
    p = __builtin_fma(p, r,  1.66666666666667e-01);
    p = __builtin_fma(p, r,  5.00000000000000e-01);
    p = __builtin_fma(p, r,  1.0);
    p = __builtin_fma(p, r,  1.0);
    const long long bits = (long long)(1023 + k) << 52;
    return p * __longlong_as_double(bits);
}

#if __has_builtin(__builtin_amdgcn_rcpf)
__device__ __forceinline__ float rcp_nr(float x) {   // ~0.5 ulp: v_rcp + 1 NR
    float r = __builtin_amdgcn_rcpf(x);
    return __builtin_fmaf(__builtin_fmaf(-x, r, 1.0f), r, r);
}
#else
__device__ __forceinline__ float rcp_nr(float x) { return 1.0f / x; }
#endif

// hardware exp (v_mul + v_exp_f32, rel err ~2.4e-6). One-sided clamp only:
// underflow -> exact 0.0 (safe); overflow (arg > ~88) would give inf -> NaN.
__device__ __forceinline__ float exp_hw_hi(float x) { return __expf(fminf(x, 40.0f)); }

// ============================================================================
// FUSED kernel (r14/r15 structure): f32 fast path (16 lanes/ray, 4
// intervals/lane, lane-per-sample emission) + inline group-uniform f64 redo
// for flagged rays. r16 changes (hot path -19%):
//  - box test via max3: inner = (amax <= 0.6); flip band only |amax-0.6|<1e-5
//    (only the max coordinate decides `inner` -> band on amax is exact+safe)
//  - one-sided exp clamp (underflow-to-0 is exact)
// ============================================================================
__global__ __launch_bounds__(256) void neus_fused_kernel(
    const float* __restrict__ rays_o,
    const float* __restrict__ rays_d,
    const float* __restrict__ z_vals,
    const float* __restrict__ sdf,
    const float* __restrict__ inv_s,
    float* __restrict__ out,
    int B)
{
    const int tid  = blockIdx.x * 256 + threadIdx.x;
    const int ray  = tid >> 4;          // 16 lanes per ray
    const int sub  = tid & 15;
    if (ray >= B) return;

    const int lane = threadIdx.x & 63;
    const int gb   = lane & ~15;        // ray-group base lane
    const int g4   = lane & ~3;         // 4-lane subgroup base
    const int s4   = sub & 3;
    const int gq   = sub >> 2;

    const float* zp = z_vals + (size_t)ray * 64 + sub * 4;
    const float* sp = sdf    + (size_t)ray * 64 + sub * 4;
    const float* ip = inv_s  + (size_t)ray * 63 + sub * 4;

    const float ox = rays_o[(size_t)ray*3+0];
    const float oy = rays_o[(size_t)ray*3+1];
    const float oz = rays_o[(size_t)ray*3+2];
    const float dx = rays_d[(size_t)ray*3+0];
    const float dy = rays_d[(size_t)ray*3+1];
    const float dz = rays_d[(size_t)ray*3+2];

    // ==================== f32 fast path ====================
    float z[5], s[5];
    {
        const float4 a = *reinterpret_cast<const float4*>(zp);
        const float4 b = *reinterpret_cast<const float4*>(sp);
        z[0]=a.x; z[1]=a.y; z[2]=a.z; z[3]=a.w;
        s[0]=b.x; s[1]=b.y; s[2]=b.z; s[3]=b.w;
    }
    z[4] = __shfl_down(z[0], 1);
    s[4] = __shfl_down(s[0], 1);

    float iv[4];
    iv[0] = ip[0]; iv[1] = ip[1]; iv[2] = ip[2];
    iv[3] = (sub < 15) ? ip[3] : 0.0f;

    int flag = 0;
    unsigned m = 0;
    #pragma unroll
    for (int i = 0; i < 4; ++i) {
        const float px = __builtin_fmaf(dx, z[i], ox);
        const float py = __builtin_fmaf(dy, z[i], oy);
        const float pz = __builtin_fmaf(dz, z[i], oz);
        // only the max coord decides inner; band on amax is exact and safe
        const float amax = fmaxf(fmaxf(fabsf(px), fabsf(py)), fabsf(pz));
        if (amax <= 0.6f) m |= (1u << i);
        flag |= (fabsf(amax - 0.6f) < 1e-5f);
    }
    m |= (__shfl_down(m, 1) & 1u) << 4;

    const float cv0_last = (s[4]-s[3]) * rcp_nr(z[4]-z[3] + 1e-5f);
    float prevc = __shfl_up(cv0_last, 1);
    if (sub == 0) prevc = 0.0f;

    float w[4], g[4];
    float Gloc = 1.0f;
    #pragma unroll
    for (int i = 0; i < 4; ++i) {
        const float cv0 = (s[i+1]-s[i]) * rcp_nr(z[i+1]-z[i] + 1e-5f);
        float cv = fminf(prevc, cv0);
        prevc = cv0;
        const float inside = ((m >> i) & 3u) ? 1.0f : 0.0f;
        cv = fminf(fmaxf(cv, -1000.f), 0.f) * inside;
        const float mid = 0.5f * (s[i] + s[i+1]);
        const float dzz = z[i+1] - z[i];
        const float q2  = cv * (dzz * 0.5f);
        const float apv = (mid - q2) * iv[i];
        const float anv = (mid + q2) * iv[i];
        const float ea = exp_hw_hi(-apv);
        const float eb = exp_hw_hi(-anv);
        const float onea = 1.f + ea;
        const float Pp  = onea * (1.f + eb);
        const float Nn  = __builtin_fmaf(1e-5f, Pp, eb - ea);
        const float Dd  = __builtin_fmaf(1e-5f, Pp, 1.f + eb);
        const float invD = rcp_nr(Dd);
        float al = Nn * invD;
        float gg = __builtin_fmaf(onea, invD, 1e-7f);
        if (i == 3 && sub == 15) { al = 0.f; gg = 1.f; }
        w[i] = al; g[i] = gg;
        Gloc *= gg;
    }

    {   // T0: hierarchical product (4x4)
        const float Ga = __shfl(Gloc, g4+0);
        const float Gb = __shfl(Gloc, g4+1);
        const float Gc = __shfl(Gloc, g4+2);
        const float Gd = __shfl(Gloc, g4+3);
        float Tw = 1.0f;
        if (s4 > 0) Tw = Ga;
        if (s4 > 1) Tw *= Gb;
        if (s4 > 2) Tw *= Gc;
        const float Gg = ((Ga*Gb)*Gc)*Gd;
        const float PA = __shfl(Gg, gb+0);
        const float PB = __shfl(Gg, gb+4);
        const float PC = __shfl(Gg, gb+8);
        float Pp = 1.0f;
        if (gq > 0) Pp = PA;
        if (gq > 1) Pp *= PB;
        if (gq > 2) Pp *= PC;
        Gloc = Pp * Tw;                 // T0
    }

    float Tr = Gloc, Sloc = 0.0f;
    #pragma unroll
    for (int i = 0; i < 4; ++i) {
        float ww = __builtin_fmaf(w[i], Tr, 1e-5f);
        if (i == 3 && sub == 15) ww = 0.0f;
        Tr *= g[i];
        Sloc += ww;
        w[i] = ww;
    }

    float Bc, total;
    {   // exclusive prefix (hierarchical canonical)
        const float Sa = __shfl(Sloc, g4+0);
        const float Sb = __shfl(Sloc, g4+1);
        const float Sc = __shfl(Sloc, g4+2);
        const float Sd = __shfl(Sloc, g4+3);
        float W = 0.0f;
        if (s4 > 0) W = Sa;
        if (s4 > 1) W += Sb;
        if (s4 > 2) W += Sc;
        const float Gs = ((Sa+Sb)+Sc)+Sd;
        const float GA = __shfl(Gs, gb+0);
        const float GB = __shfl(Gs, gb+4);
        const float GC = __shfl(Gs, gb+8);
        const float GD = __shfl(Gs, gb+12);
        float Pg = 0.0f;
        if (gq > 0) Pg = GA;
        if (gq > 1) Pg += GB;
        if (gq > 2) Pg += GC;
        Bc    = Pg + W;
        total = ((GA+GB)+GC)+GD;
    }
    const float bandU = 4e-5f * total;
    const float bandW = 1e-3f * total;

    const float U = __builtin_fmaf((float)sub, 0.0625f, 0.03125f) * total;

    int own = 0;
    { const float t = __shfl(Bc, gb + (own|8)); if (t <= U) own |= 8; }
    { const float t = __shfl(Bc, gb + (own|4)); if (t <= U) own |= 4; }
    { const float t = __shfl(Bc, gb + (own|2)); if (t <= U) own |= 2; }
    { const float t = __shfl(Bc, gb + (own|1)); if (t <= U) own |= 1; }
    const int ol = gb + own;

    const float Cown = __shfl(Bc, ol);
    const float w0 = __shfl(w[0], ol);
    const float w1 = __shfl(w[1], ol);
    const float w2 = __shfl(w[2], ol);
    const float w3 = __shfl(w[3], ol);
    const float za = __shfl(z[0], ol);
    const float zb = __shfl(z[1], ol);
    const float zc = __shfl(z[2], ol);
    const float zd = __shfl(z[3], ol);
    const float ze = __shfl(z[4], ol);
    const float wpB = __shfl(w[3], max(ol-1, 0));
    const float wnB = __shfl(w[0], min(ol+1, 63));

    const float c1 = Cown + w0, c2 = c1 + w1, c3 = c2 + w2;
    const int j = (U >= c1) + (U >= c2) + (U >= c3);
    const float cj  = (j==0)?Cown:(j==1)?c1:(j==2)?c2:c3;
    const float wj  = (j==0)?w0:(j==1)?w1:(j==2)?w2:w3;
    const float zj  = (j==0)?za:(j==1)?zb:(j==2)?zc:zd;
    const float zj1 = (j==0)?zb:(j==1)?zc:(j==2)?zd:ze;
    const float wprev = (j==0)?wpB:(j==1)?w0:(j==2)?w1:w2;
    const float wnext = (j==0)?w1:(j==1)?w2:(j==2)?w3:wnB;

    flag |= (wj < bandW);
    flag |= (((U - cj) < bandU) & (wprev < bandW));
    flag |= (((cj + wj - U) < bandU) & (wnext < bandW));

    const float tt = (U - cj) * rcp_nr(wj);
    out[(size_t)ray * NIMP + sub] = __builtin_fmaf(tt, zj1 - zj, zj);

    // ---- group-uniform flag ----
    int fl = flag;
    fl |= __shfl_xor(fl, 1);
    fl |= __shfl_xor(fl, 2);
    fl |= __shfl_xor(fl, 4);
    fl |= __shfl_xor(fl, 8);

    if (!fl) return;

    // ==================== inline f64 redo (rare, group-uniform) ====================
    const double oxd = (double)ox, oyd = (double)oy, ozd = (double)oz;
    const double dxd = (double)dx, dyd = (double)dy, dzd = (double)dz;

    double zD[5], sD[5];
    {
        const float4 a = *reinterpret_cast<const float4*>(zp);
        const float4 b = *reinterpret_cast<const float4*>(sp);
        zD[0]=a.x; zD[1]=a.y; zD[2]=a.z; zD[3]=a.w;
        sD[0]=b.x; sD[1]=b.y; sD[2]=b.z; sD[3]=b.w;
    }
    zD[4] = __shfl_down(zD[0], 1);   // sub15: garbage, provably unused
    sD[4] = __shfl_down(sD[0], 1);

    double ivD[4];
    ivD[0] = (double)ip[0]; ivD[1] = (double)ip[1]; ivD[2] = (double)ip[2];
    ivD[3] = (sub < 15) ? (double)ip[3] : 0.0;

    unsigned md = 0;
    #pragma unroll
    for (int i = 0; i < 4; ++i) {
        const double px = oxd + dxd*zD[i];
        const double py = oyd + dyd*zD[i];
        const double pz = ozd + dzd*zD[i];
        if (fabs(px) <= SIDE && fabs(py) <= SIDE && fabs(pz) <= SIDE)
            md |= (1u << i);
    }
    md |= (__shfl_down(md, 1) & 1u) << 4;

    const double cvl = (sD[4]-sD[3]) / (zD[4]-zD[3] + 1e-5);
    double pvc = __shfl_up(cvl, 1);
    if (sub == 0) pvc = 0.0;

    double wD[4], gD[4];
    double Gl = 1.0;
    #pragma unroll
    for (int i = 0; i < 4; ++i) {
        const double cv0 = (sD[i+1]-sD[i]) / (zD[i+1]-zD[i] + 1e-5);
        double cv = fmin(pvc, cv0);
        pvc = cv0;
        const double inside = ((md >> i) & 3u) ? 1.0 : 0.0;
        cv = fmin(fmax(cv, -1000.0), 0.0) * inside;
        const double mid  = 0.5 * (sD[i] + sD[i+1]);
        const double dist = zD[i+1] - zD[i];
        const double arg_p = (mid - cv * dist * 0.5) * ivD[i];
        const double arg_n = (mid + cv * dist * 0.5) * ivD[i];
        const double a = exp_fast(fmin(fmax(-arg_p, -350.0), 350.0));
        const double b = exp_fast(fmin(fmax(-arg_n, -350.0), 350.0));
        const double P = (1.0 + a) * (1.0 + b);
        double alpha = (__builtin_fma(1e-5, P, b - a)) /
                       (__builtin_fma(1e-5, P, 1.0 + b));
        double gg = 1.0 - alpha + 1e-7;
        if (i == 3 && sub == 15) { alpha = 0.0; gg = 1.0; }
        wD[i] = alpha; gD[i] = gg;
        Gl *= gg;
    }

    {   // T0 hierarchical (f64)
        const double Ga = __shfl(Gl, g4+0);
        const double Gb = __shfl(Gl, g4+1);
        const double Gc = __shfl(Gl, g4+2);
        const double Gd = __shfl(Gl, g4+3);
        double Tw = 1.0;
        if (s4 > 0) Tw = Ga;
        if (s4 > 1) Tw *= Gb;
        if (s4 > 2) Tw *= Gc;
        const double Gg = ((Ga*Gb)*Gc)*Gd;
        const double PA = __shfl(Gg, gb+0);
        const double PB = __shfl(Gg, gb+4);
        const double PC = __shfl(Gg, gb+8);
        double Pp = 1.0;
        if (gq > 0) Pp = PA;
        if (gq > 1) Pp *= PB;
        if (gq > 2) Pp *= PC;
        Gl = Pp * Tw;                    // T0
    }

    double TrD = Gl, Sl = 0.0;
    #pragma unroll
    for (int i = 0; i < 4; ++i) {
        double ww = wD[i] * TrD + 1e-5;
        if (i == 3 && sub == 15) ww = 0.0;
        TrD *= gD[i];
        Sl += ww;
        wD[i] = ww;
    }

    double BcD, totD;
    {
        const double Sa = __shfl(Sl, g4+0);
        const double Sb = __shfl(Sl, g4+1);
        const double Sc = __shfl(Sl, g4+2);
        const double Sd = __shfl(Sl, g4+3);
        double W = 0.0;
        if (s4 > 0) W = Sa;
        if (s4 > 1) W += Sb;
        if (s4 > 2) W += Sc;
        const double Gs = ((Sa+Sb)+Sc)+Sd;
        const double GA = __shfl(Gs, gb+0);
        const double GB = __shfl(Gs, gb+4);
        const double GC = __shfl(Gs, gb+8);
        const double GD = __shfl(Gs, gb+12);
        double Pg = 0.0;
        if (gq > 0) Pg = GA;
        if (gq > 1) Pg += GB;
        if (gq > 2) Pg += GC;
        BcD  = Pg + W;
        totD = ((GA+GB)+GC)+GD;
    }

    const double ud = 0.03125 + 0.0625 * (double)sub;   // exact

    int ow = 0;   // largest q with cdf(Bc_q) <= u (division form, as r4)
    { const double t = __shfl(BcD, gb + (ow|8)); if (t/totD <= ud) ow |= 8; }
    { const double t = __shfl(BcD, gb + (ow|4)); if (t/totD <= ud) ow |= 4; }
    { const double t = __shfl(BcD, gb + (ow|2)); if (t/totD <= ud) ow |= 2; }
    { const double t = __shfl(BcD, gb + (ow|1)); if (t/totD <= ud) ow |= 1; }
    const int ol2 = gb + ow;

    const double CoD = __shfl(BcD, ol2);
    const double u0D = __shfl(wD[0], ol2);
    const double u1D = __shfl(wD[1], ol2);
    const double u2D = __shfl(wD[2], ol2);
    const double u3D = __shfl(wD[3], ol2);
    const double zaD = __shfl(zD[0], ol2);
    const double zbD = __shfl(zD[1], ol2);
    const double zcD = __shfl(zD[2], ol2);
    const double zdD = __shfl(zD[3], ol2);
    const double zeD = __shfl(zD[4], ol2);

    const double d1 = CoD + u0D, d2 = d1 + u1D, d3 = d2 + u2D;
    const int jj = (d1/totD <= ud) + (d2/totD <= ud) + (d3/totD <= ud);
    const double cjD  = (jj==0)?CoD:(jj==1)?d1:(jj==2)?d2:d3;
    const double wjD  = (jj==0)?u0D:(jj==1)?u1D:(jj==2)?u2D:u3D;
    const double zjD  = (jj==0)?zaD:(jj==1)?zbD:(jj==2)?zcD:zdD;
    const double zj1D = (jj==0)?zbD:(jj==1)?zcD:(jj==2)?zdD:zeD;

    const double cdfb = cjD / totD;
    const double cdfa = (cjD + wjD) / totD;
    double den = cdfa - cdfb;
    den = (den < 1e-5) ? 1.0 : den;
    const double tD = (ud - cdfb) / den;
    const double rD = zjD + tD * (zj1D - zjD);

    out[(size_t)ray * NIMP + sub] = (float)rD;
}

// ============================================================================
// Fallback (n != 16): validated r4/r7 f64 wave-per-ray over ALL rays.
// ============================================================================
__global__ __launch_bounds__(256) void neus_redo_kernel(
    const float* __restrict__ rays_o,
    const float* __restrict__ rays_d,
    const float* __restrict__ z_vals,
    const float* __restrict__ sdf,
    const float* __restrict__ inv_s,
    float* __restrict__ out,
    int B, int n_imp, double u0, double du)
{
    const int lane = threadIdx.x & 63;
    const int wv   = blockIdx.x * 4 + (threadIdx.x >> 6);

    for (unsigned i = wv; i < (unsigned)B; i += 1024) {
        const int ray = (int)i;

        const double z = (double)z_vals[(size_t)ray * 64 + lane];
        const double s = (double)sdf   [(size_t)ray * 64 + lane];
        double isv = 0.0;
        if (lane < 63) isv = (double)inv_s[(size_t)ray * 63 + lane];

        const double ox = (double)rays_o[(size_t)ray*3+0];
        const double oy = (double)rays_o[(size_t)ray*3+1];
        const double oz = (double)rays_o[(size_t)ray*3+2];
        const double dx = (double)rays_d[(size_t)ray*3+0];
        const double dy = (double)rays_d[(size_t)ray*3+1];
        const double dz = (double)rays_d[(size_t)ray*3+2];

        const double px = ox + dx*z, py = oy + dy*z, pz = oz + dz*z;
        const double inner = (fabs(px) <= SIDE && fabs(py) <= SIDE && fabs(pz) <= SIDE) ? 1.0 : 0.0;

        const double next_s  = __shfl_down(s, 1);
        const double next_z  = __shfl_down(z, 1);
        const double inner_n = __shfl_down(inner, 1);

        const double inside = ((inner > 0.5) || (inner_n > 0.5)) ? 1.0 : 0.0;
        const double mid    = 0.5 * (s + next_s);
        const double cv0    = (next_s - s) / (next_z - z + 1e-5);
        double prevc = __shfl_up(cv0, 1);
        if (lane == 0) prevc = 0.0;
        double cv = fmin(prevc, cv0);
        cv = fmin(fmax(cv, -1000.0), 0.0) * inside;
        const double dist = next_z - z;

        const double arg_p = (mid - cv * dist * 0.5) * isv;
        const double arg_n = (mid + cv * dist * 0.5) * isv;
        const double a = exp_fast(fmin(fmax(-arg_p, -350.0), 350.0));
        const double b = exp_fast(fmin(fmax(-arg_n, -350.0), 350.0));
        const double P = (1.0 + a) * (1.0 + b);
        const double alpha = (__builtin_fma(1e-5, P, b - a)) /
                             (__builtin_fma(1e-5, P, 1.0 + b));

        double g = (lane < 63) ? (1.0 - alpha + 1e-7) : 1.0;
        double p = g;
        #pragma unroll
        for (int off = 1; off < 64; off <<= 1) {
            double tmp = __shfl_up(p, off);
            if (lane >= off) p *= tmp;
        }
        double trans = __shfl_up(p, 1);
        if (lane == 0) trans = 1.0;

        const double w = (lane < 63) ? (alpha * trans + 1e-5) : 0.0;

        double sc = w;
        #pragma unroll
        for (int off = 1; off < 64; off <<= 1) {
            double tmp = __shfl_up(sc, off);
            if (lane >= off) sc += tmp;
        }
        const double total = __shfl(sc, 63);
        const double excl  = sc - w;
        const double cdf   = excl / total;

        const double u = u0 + du * (double)lane;
        int lo = 0, hi = 64;
        #pragma unroll
        for (int it = 0; it < 7; ++it) {
            const int m  = (lo + hi) >> 1;
            const double cm = __shfl(cdf, m);
            if (lo < hi) {
                if (cm <= u) lo = m + 1; else hi = m;
            }
        }
        const int ind   = lo;
        const int below = max(ind - 1, 0);
        const int above = min(ind, 63);

        const double cb = __shfl(cdf, below);
        const double ca = __shfl(cdf, above);
        const double bb = __shfl(z, below);
        const double ba = __shfl(z, above);

        double denom = ca - cb;
        denom = (denom < 1e-5) ? 1.0 : denom;
        const double tt  = (u - cb) / denom;
        const double r2  = bb + tt * (ba - bb);

        if (lane < n_imp) out[(size_t)ray * n_imp + lane] = (float)r2;
    }
}

extern "C" void kernel_launch(void* const* d_in, const int* in_sizes, int n_in,
                              void* d_out, int out_size, void* d_ws, size_t ws_size,
                              hipStream_t stream) {
    const float* rays_o = (const float*)d_in[0];
    const float* rays_d = (const float*)d_in[1];
    const float* z_vals = (const float*)d_in[2];
    const float* sdf    = (const float*)d_in[3];
    const float* inv_s  = (const float*)d_in[4];
    float* out = (float*)d_out;

    const int B = in_sizes[0] / 3;          // 131072
    const int n = out_size / B;             // n_importance = 16

    if (n == NIMP) {
        const long long threads = (long long)B * 16;
        neus_fused_kernel<<<(int)((threads + 255) / 256), 256, 0, stream>>>(
            rays_o, rays_d, z_vals, sdf, inv_s, out, B);
    } else {
        const double u0 = 0.5 / (double)n;
        const double du = (n > 1) ? ((1.0 - 1.0 / (double)n) / (double)(n - 1)) : 0.0;
        neus_redo_kernel<<<256, 256, 0, stream>>>(
            rays_o, rays_d, z_vals, sdf, inv_s, out, B, n, u0, du);
    }
}